// Round 10
// baseline (786.484 us; speedup 1.0000x reference)
//
#include <hip/hip_runtime.h>
#include <cmath>

typedef _Float16 f16;
typedef __attribute__((ext_vector_type(8))) _Float16 f16x8;
typedef __attribute__((ext_vector_type(4))) _Float16 f16x4;
typedef __attribute__((ext_vector_type(4))) float f32x4;

struct TileInfo { int m0, mcnt, e, pad; };

__device__ __forceinline__ void gload16(const void* g, void* l) {
  __builtin_amdgcn_global_load_lds((const __attribute__((address_space(1))) void*)g,
                                   (__attribute__((address_space(3))) void*)l, 16, 0, 0);
}

// fast gelu: 0.5u(1+tanh(c)) = u*e/(e+1), e=exp(2c), c=0.79788456(u+0.044715u^3)
__device__ __forceinline__ float fast_gelu(float u) {
  const float c = u * (0.7978845608028654f + 0.0356774081f * u * u);
  const float t = fminf(2.0f * c, 80.0f);
  const float e = __expf(t);
  return u * (e * __builtin_amdgcn_rcpf(e + 1.0f));
}

// ---------------------------------------------------------------------------
// Unified GEMM with XCD-aware block swizzle (grid size % 8 == 0 required):
// each XCD gets a contiguous run of linear block ids -> same-N blocks share
// the B panel in that XCD's private L2 (shorter staging latency, less HBM).
//   NPASS==1: BK=64, LDS double-buffer (2x32KB), counted vmcnt(8) (R7 proven).
//   NPASS==3: BK=64, single 64KB buffer (Ah/Al/Bh/Bl planes), R7 proven.
// MODE: 0 direct, 1 rowmap, 2 tile-table (MoE), 3 conv (zero-pad via zbuf).
// EPI: 0 f32=acc+bias; 1 f32=res+acc+bias; 2 f16=acc+bias; 3 f16=gelu(acc+bias)
// ---------------------------------------------------------------------------
template<int NPASS, int MODE, int EPI>
__global__ __launch_bounds__(256)
void gemm_kernel(const f16* __restrict__ Ah, const f16* __restrict__ Al, int lda,
                 const f16* __restrict__ Bh, const f16* __restrict__ Bl, int ldb,
                 const float* __restrict__ bias, const float* __restrict__ res,
                 float* __restrict__ outf, f16* __restrict__ outh, int ldo, int K,
                 const int* __restrict__ rowmap, const TileInfo* __restrict__ table,
                 const char* __restrict__ zbuf) {
  __shared__ __align__(16) char lds[65536];

  const int tid  = threadIdx.x;
  const int wave = tid >> 6;
  const int lane = tid & 63;

  // XCD swizzle: nwg % 8 == 0 for every launch in this file.
  const int gx  = gridDim.x;
  const int lid = blockIdx.x + blockIdx.y * gx;
  const int per = (gx * gridDim.y) >> 3;
  const int swz = (lid & 7) * per + (lid >> 3);
  const int bx  = swz % gx;
  const int by  = swz / gx;

  int m0, mcnt, eidx = 0;
  if (MODE == 2) {
    TileInfo ti = table[bx];
    if (ti.mcnt <= 0) return;
    m0 = ti.m0; mcnt = ti.mcnt; eidx = ti.e;
  } else { m0 = bx * 128; mcnt = 128; }
  const int n0 = by * 128;

  const f16* Bh_ = Bh;
  const float* bias_ = bias;
  size_t adelta = 0, bdelta = 0;
  if (NPASS == 3) {
    adelta = (size_t)((const char*)Al - (const char*)Ah);
    bdelta = (size_t)((const char*)Bl - (const char*)Bh);
  }
  if (MODE == 2) { Bh_ += ((size_t)eidx << 20); bias_ += eidx * 1024; }

  f32x4 acc[4][4] = {};
  const int wm  = (wave >> 1) * 64;
  const int wn  = (wave & 1) * 64;
  const int fr  = lane & 15;
  const int kgb = (lane >> 4) * 16;
  const int wuni = wave * 1024;

  const int sr    = tid / 8;          // 0..31
  const int cbyte = (tid % 8) * 16;

  if constexpr (NPASS == 1) {
    // ---- BK=64 double-buffered counted-vmcnt (R7, proven) ----
    const char* aSrc[4];
    const char* bSrc[4];
    #pragma unroll
    for (int r = 0; r < 4; ++r) {
      const int mr  = sr + r * 32;
      const int cbs = cbyte ^ ((mr & 7) << 4);
      int gi = m0 + ((mr < mcnt) ? mr : (mcnt - 1));
      if (MODE == 1 || MODE == 2) gi = rowmap[gi];
      aSrc[r] = (const char*)Ah + (size_t)gi * lda * 2 + cbs;
      bSrc[r] = (const char*)Bh_ + (size_t)(n0 + mr) * ldb * 2 + cbs;
    }
    const int NT = K / 64;
    #pragma unroll
    for (int r = 0; r < 4; ++r) {
      gload16(aSrc[r], lds + r * 4096 + wuni);
      gload16(bSrc[r], lds + 16384 + r * 4096 + wuni);
    }
    #pragma unroll
    for (int r = 0; r < 4; ++r) {
      gload16(aSrc[r] + 128, lds + 32768 + r * 4096 + wuni);
      gload16(bSrc[r] + 128, lds + 32768 + 16384 + r * 4096 + wuni);
    }
    asm volatile("s_waitcnt vmcnt(8)" ::: "memory");
    __builtin_amdgcn_s_barrier();

    for (int kt = 0; kt < NT; ++kt) {
      const int c = kt & 1;
      const char* LAp = lds + c * 32768;
      const char* LBp = LAp + 16384;
      f16x8 ah[2][4], bh[2][4];
      #pragma unroll
      for (int kk = 0; kk < 2; ++kk) {
        #pragma unroll
        for (int i = 0; i < 4; ++i) {
          const int ar = wm + i * 16 + fr;
          ah[kk][i] = *(const f16x8*)(LAp + ar * 128 + ((kk * 64 + kgb) ^ ((ar & 7) << 4)));
          const int br = wn + i * 16 + fr;
          bh[kk][i] = *(const f16x8*)(LBp + br * 128 + ((kk * 64 + kgb) ^ ((br & 7) << 4)));
        }
      }
      asm volatile("s_waitcnt lgkmcnt(0)" ::: "memory");
      __builtin_amdgcn_s_barrier();
      if (kt + 2 < NT) {
        const size_t ko = (size_t)(kt + 2) * 128;
        #pragma unroll
        for (int r = 0; r < 4; ++r) {
          gload16(aSrc[r] + ko, lds + c * 32768 + r * 4096 + wuni);
          gload16(bSrc[r] + ko, lds + c * 32768 + 16384 + r * 4096 + wuni);
        }
      }
      #pragma unroll
      for (int kk = 0; kk < 2; ++kk)
        #pragma unroll
        for (int i = 0; i < 4; ++i)
          #pragma unroll
          for (int j = 0; j < 4; ++j)
            acc[i][j] = __builtin_amdgcn_mfma_f32_16x16x32_f16(ah[kk][i], bh[kk][j], acc[i][j], 0, 0, 0);
      if (kt + 2 < NT) asm volatile("s_waitcnt vmcnt(8)" ::: "memory");
      else             asm volatile("s_waitcnt vmcnt(0)" ::: "memory");
      __builtin_amdgcn_s_barrier();
    }
  } else {
    // ---- NPASS==3: single-buffered 3-pass loop (R7, proven) ----
    const char* aSrcB[4]; const char* bSrcB[4];
    int aRowC[4], aCbs[4];
    #pragma unroll
    for (int r = 0; r < 4; ++r) {
      const int mr  = sr + r * 32;
      const int cbs = cbyte ^ ((mr & 7) << 4);
      int gi = m0 + mr;
      if (MODE == 1) gi = rowmap[gi];
      if (MODE == 3) { aRowC[r] = gi; aCbs[r] = cbs; aSrcB[r] = nullptr; }
      else           { aSrcB[r] = (const char*)Ah + (size_t)gi * lda * 2 + cbs; aRowC[r] = 0; aCbs[r] = 0; }
      bSrcB[r] = (const char*)Bh_ + (size_t)(n0 + mr) * ldb * 2 + cbs;
    }
    for (int k0 = 0; k0 < K; k0 += 64) {
      #pragma unroll
      for (int r = 0; r < 4; ++r) {
        const char* as; const char* asl;
        if (MODE == 3) {
          const int tap = k0 >> 10;
          const int kc  = k0 & 1023;
          const int tok = aRowC[r] & 4095;
          const int stk = tok + (tap - 1) * 2;
          if (stk >= 0 && stk < 4096) {
            as  = (const char*)Ah + (size_t)(aRowC[r] + (tap - 1) * 2) * 2048 + kc * 2 + aCbs[r];
            asl = as + adelta;
          } else { as = zbuf; asl = zbuf; }
        } else {
          as  = aSrcB[r] + (size_t)k0 * 2;
          asl = as + adelta;
        }
        gload16(as,  lds + 0     + r * 4096 + wuni);
        gload16(asl, lds + 16384 + r * 4096 + wuni);
        const char* bs = bSrcB[r] + (size_t)k0 * 2;
        gload16(bs,          lds + 32768 + r * 4096 + wuni);
        gload16(bs + bdelta, lds + 49152 + r * 4096 + wuni);
      }
      __syncthreads();
      #pragma unroll
      for (int kk = 0; kk < 2; ++kk) {
        f16x8 ah[4], al[4], bh[4], bl[4];
        #pragma unroll
        for (int i = 0; i < 4; ++i) {
          const int ar = wm + i * 16 + fr;
          const int ao = ar * 128 + ((kk * 64 + kgb) ^ ((ar & 7) << 4));
          ah[i] = *(const f16x8*)(lds + ao);
          al[i] = *(const f16x8*)(lds + 16384 + ao);
          const int br = wn + i * 16 + fr;
          const int bo = br * 128 + ((kk * 64 + kgb) ^ ((br & 7) << 4));
          bh[i] = *(const f16x8*)(lds + 32768 + bo);
          bl[i] = *(const f16x8*)(lds + 49152 + bo);
        }
        #pragma unroll
        for (int i = 0; i < 4; ++i) {
          #pragma unroll
          for (int j = 0; j < 4; ++j) {
            acc[i][j] = __builtin_amdgcn_mfma_f32_16x16x32_f16(ah[i], bh[j], acc[i][j], 0, 0, 0);
            acc[i][j] = __builtin_amdgcn_mfma_f32_16x16x32_f16(ah[i], bl[j], acc[i][j], 0, 0, 0);
            acc[i][j] = __builtin_amdgcn_mfma_f32_16x16x32_f16(al[i], bh[j], acc[i][j], 0, 0, 0);
          }
        }
      }
      __syncthreads();
    }
  }

  #pragma unroll
  for (int i = 0; i < 4; ++i) {
    const int mb = wm + i * 16 + (lane >> 4) * 4;
    #pragma unroll
    for (int j = 0; j < 4; ++j) {
      const int nc = n0 + wn + j * 16 + fr;
      const float bv = bias_[nc];
      #pragma unroll
      for (int q = 0; q < 4; ++q) {
        const int ml = mb + q;
        if (MODE == 2 && ml >= mcnt) continue;
        const size_t orow = (size_t)(m0 + ml);
        float v = acc[i][j][q] + bv;
        if (EPI == 1) v += res[orow * ldo + nc];
        if (EPI == 3) v = fast_gelu(v);
        if (EPI <= 1) outf[orow * ldo + nc] = v;
        else          outh[orow * ldo + nc] = (f16)v;
      }
    }
  }
}

// ---------------------------------------------------------------------------
// LayerNorm: fp32 in -> f16 hi (+optional lo plane). WGATE: fused gate logits.
// COMPACT: read source row (row<2176 ? row : row+1920), write compact row —
// produces exactly the 4352 rows the QKV GEMM consumes.
// ---------------------------------------------------------------------------
template<int WLO, int WGATE, int COMPACT>
__global__ __launch_bounds__(256)
void ln_kernel(const float* __restrict__ x, const float* __restrict__ g, const float* __restrict__ b,
               f16* __restrict__ oh, f16* __restrict__ ol,
               const float* __restrict__ gW, const float* __restrict__ gb,
               float* __restrict__ logits) {
  const int row = blockIdx.x;
  const int srow = COMPACT ? ((row < 2176) ? row : row + 1920) : row;
  const int t = threadIdx.x;
  const float4 v = ((const float4*)(x + (size_t)srow * 1024))[t];
  float s  = v.x + v.y + v.z + v.w;
  float ss = v.x * v.x + v.y * v.y + v.z * v.z + v.w * v.w;
  #pragma unroll
  for (int off = 32; off; off >>= 1) { s += __shfl_down(s, off, 64); ss += __shfl_down(ss, off, 64); }
  __shared__ float red[8];
  if ((t & 63) == 0) { red[t >> 6] = s; red[(t >> 6) + 4] = ss; }
  __syncthreads();
  s  = red[0] + red[1] + red[2] + red[3];
  ss = red[4] + red[5] + red[6] + red[7];
  const float mu  = s * (1.0f / 1024.0f);
  const float var = ss * (1.0f / 1024.0f) - mu * mu;
  const float inv = 1.0f / sqrtf(var + 1e-5f);
  const float4 gv = ((const float4*)g)[t];
  const float4 bv = ((const float4*)b)[t];
  float y[4];
  y[0] = (v.x - mu) * inv * gv.x + bv.x;
  y[1] = (v.y - mu) * inv * gv.y + bv.y;
  y[2] = (v.z - mu) * inv * gv.z + bv.z;
  y[3] = (v.w - mu) * inv * gv.w + bv.w;
  f16x4 hv;
  #pragma unroll
  for (int u = 0; u < 4; ++u) hv[u] = (f16)y[u];
  *(f16x4*)(oh + (size_t)row * 1024 + t * 4) = hv;
  if (WLO) {
    f16x4 lv;
    #pragma unroll
    for (int u = 0; u < 4; ++u) lv[u] = (f16)(y[u] - (float)hv[u]);
    *(f16x4*)(ol + (size_t)row * 1024 + t * 4) = lv;
  }
  if (WGATE) {
    const float* gr = gW + (size_t)(t * 4) * 8;
    float lg[8];
    #pragma unroll
    for (int e = 0; e < 8; ++e)
      lg[e] = y[0] * gr[e] + y[1] * gr[8 + e] + y[2] * gr[16 + e] + y[3] * gr[24 + e];
    #pragma unroll
    for (int m = 1; m < 64; m <<= 1)
      #pragma unroll
      for (int e = 0; e < 8; ++e) lg[e] += __shfl_xor(lg[e], m, 64);
    __shared__ float gred[4][8];
    if ((t & 63) == 0) {
      #pragma unroll
      for (int e = 0; e < 8; ++e) gred[t >> 6][e] = lg[e];
    }
    __syncthreads();
    if (t < 8)
      logits[(size_t)row * 8 + t] = gred[0][t] + gred[1][t] + gred[2][t] + gred[3][t] + gb[t];
  }
}

// ---------------------------------------------------------------------------
// Windowed attention (512 thr/block): see R6.
// ---------------------------------------------------------------------------
__global__ __launch_bounds__(512, 4)
void attn_kernel(const float* __restrict__ qkv, f16* __restrict__ oh, f16* __restrict__ ol) {
  __shared__ __align__(16) char sm[81920];
  const int bid = blockIdx.x;
  const int b = bid >> 8, h = (bid >> 4) & 15, n = bid & 15;
  const int t = threadIdx.x;
  const size_t rowbase = (size_t)(b * 2176 + n * 128);
  const char* qg = (const char*)(qkv + rowbase * 3072 + h * 64);
  const char* kg = qg + 4096;
  const char* vg = qg + 8192;

  const int srow = t >> 4;
  const int scol = (t & 15) * 16;
  const int wuni = (t >> 6) * 1024;

  const int dt = t >> 4;
  const int et = t & 15;
  float pacc[2][4] = {};

  for (int r = 0; r < 2; ++r) {
    #pragma unroll
    for (int p = 0; p < 4; ++p) {
      const size_t off = (size_t)(r * 128 + p * 32 + srow) * 12288 + scol;
      gload16(qg + off, sm + p * 8192 + wuni);
      gload16(kg + off, sm + 32768 + p * 8192 + wuni);
    }
    __syncthreads();
    #pragma unroll 4
    for (int s = 0; s < 128; ++s) {
      const float2 q2 = *(const float2*)(sm + s * 256 + dt * 8);
      const f32x4 k4 = *(const f32x4*)(sm + 32768 + s * 256 + et * 16);
      #pragma unroll
      for (int z = 0; z < 4; ++z) {
        pacc[0][z] += q2.x * k4[z];
        pacc[1][z] += q2.y * k4[z];
      }
    }
    __syncthreads();
  }

  #pragma unroll
  for (int i = 0; i < 2; ++i) {
    #pragma unroll
    for (int z = 0; z < 4; ++z) pacc[i][z] *= 0.125f;
    float m = fmaxf(fmaxf(pacc[i][0], pacc[i][1]), fmaxf(pacc[i][2], pacc[i][3]));
    m = fmaxf(m, __shfl_xor(m, 1, 16));
    m = fmaxf(m, __shfl_xor(m, 2, 16));
    m = fmaxf(m, __shfl_xor(m, 4, 16));
    m = fmaxf(m, __shfl_xor(m, 8, 16));
    float den = 0.0f;
    #pragma unroll
    for (int z = 0; z < 4; ++z) { pacc[i][z] = __expf(pacc[i][z] - m); den += pacc[i][z]; }
    den += __shfl_xor(den, 1, 16);
    den += __shfl_xor(den, 2, 16);
    den += __shfl_xor(den, 4, 16);
    den += __shfl_xor(den, 8, 16);
    const float dinv = 1.0f / den;
    f32x4 pv;
    #pragma unroll
    for (int z = 0; z < 4; ++z) pv[z] = pacc[i][z] * dinv;
    *(f32x4*)(sm + 65536 + (dt * 2 + i) * 256 + et * 16) = pv;
  }

  const int dt2 = t & 15;
  const int st  = t >> 4;
  const int ch  = h * 64 + (st & 15) * 4;
  const size_t rb2 = (size_t)(b * 4096 + n * 256);

  for (int c = 0; c < 2; ++c) {
    __syncthreads();
    #pragma unroll
    for (int p = 0; p < 4; ++p) {
      const size_t off = (size_t)(c * 128 + p * 32 + srow) * 12288 + scol;
      gload16(vg + off, sm + p * 8192 + wuni);
    }
    __syncthreads();
    float o[16];
    #pragma unroll
    for (int u = 0; u < 16; ++u) o[u] = 0.0f;
    #pragma unroll 2
    for (int e4 = 0; e4 < 16; ++e4) {
      f32x4 p4[4], v4[4];
      #pragma unroll
      for (int i = 0; i < 4; ++i)
        p4[i] = *(const f32x4*)(sm + 65536 + (dt2 * 4 + i) * 256 + e4 * 16);
      #pragma unroll
      for (int j = 0; j < 4; ++j)
        v4[j] = *(const f32x4*)(sm + (st * 4 + j) * 256 + e4 * 16);
      #pragma unroll
      for (int j = 0; j < 4; ++j)
        #pragma unroll
        for (int i = 0; i < 4; ++i) {
          o[j * 4 + i] += v4[j][0] * p4[i][0] + v4[j][1] * p4[i][1]
                        + v4[j][2] * p4[i][2] + v4[j][3] * p4[i][3];
        }
    }
    const int rq = c * 2 + (st >> 4);
    #pragma unroll
    for (int i = 0; i < 4; ++i) {
      const size_t row = rb2 + (size_t)(dt2 * 4 + i) * 4 + rq;
      f16x4 hv, lv;
      #pragma unroll
      for (int j = 0; j < 4; ++j) {
        const float val = o[j * 4 + i];
        hv[j] = (f16)val;
        lv[j] = (f16)(val - (float)hv[j]);
      }
      *(f16x4*)(oh + row * 1024 + ch) = hv;
      *(f16x4*)(ol + row * 1024 + ch) = lv;
    }
  }
}

// ---------------------------------------------------------------------------
// weight transposes fp32 -> f16 (optional lo plane); batched over blockIdx.z
// ---------------------------------------------------------------------------
template<int SPLIT>
__global__ __launch_bounds__(256)
void transpose_kernel(const float* __restrict__ in, int R, int Cc,
                      f16* __restrict__ oh, f16* __restrict__ ol) {
  __shared__ float tile[32][33];
  const size_t mat = (size_t)blockIdx.z * R * Cc;
  in += mat; oh += mat; if (SPLIT) ol += mat;
  const int tx = threadIdx.x & 31, ty = threadIdx.x >> 5;
  const int c = blockIdx.x * 32 + tx;
  #pragma unroll
  for (int j = 0; j < 32; j += 8) {
    const int r = blockIdx.y * 32 + ty + j;
    tile[ty + j][tx] = in[(size_t)r * Cc + c];
  }
  __syncthreads();
  const int rT = blockIdx.y * 32 + tx;
  #pragma unroll
  for (int j = 0; j < 32; j += 8) {
    const int cT = blockIdx.x * 32 + ty + j;
    const float v = tile[tx][ty + j];
    const f16 hv = (f16)v;
    oh[(size_t)cT * R + rT] = hv;
    if (SPLIT) ol[(size_t)cT * R + rT] = (f16)(v - (float)hv);
  }
}

// conv weights [O,I,3] -> BT[o][tap*1024+i] hi/lo
__global__ __launch_bounds__(256)
void convw_kernel(const float* __restrict__ w, f16* __restrict__ oh, f16* __restrict__ ol) {
  const int id = blockIdx.x * 256 + threadIdx.x;
  const int o = id >> 10, i = id & 1023;
  const float* ws = w + (size_t)o * 3072 + i * 3;
  #pragma unroll
  for (int tap = 0; tap < 3; ++tap) {
    const float v = ws[tap];
    const f16 hv = (f16)v;
    const size_t oi = (size_t)o * 3072 + tap * 1024 + i;
    oh[oi] = hv;
    ol[oi] = (f16)(v - (float)hv);
  }
}

// ---------------------------------------------------------------------------
// gate finalize
// ---------------------------------------------------------------------------
__global__ __launch_bounds__(256)
void gatefin_kernel(const float* __restrict__ logits, float* __restrict__ top2p,
                    int* __restrict__ top2i, float* __restrict__ ent,
                    int* __restrict__ counts) {
  __shared__ int hist[8];
  const int t = threadIdx.x;
  if (t < 8) hist[t] = 0;
  __syncthreads();
  const int token = blockIdx.x * 256 + t;
  float lg[8];
  const float4 l0 = ((const float4*)(logits + (size_t)token * 8))[0];
  const float4 l1 = ((const float4*)(logits + (size_t)token * 8))[1];
  lg[0] = l0.x; lg[1] = l0.y; lg[2] = l0.z; lg[3] = l0.w;
  lg[4] = l1.x; lg[5] = l1.y; lg[6] = l1.z; lg[7] = l1.w;
  int i0 = 0; float v0 = lg[0];
  #pragma unroll
  for (int e = 1; e < 8; ++e) if (lg[e] > v0) { v0 = lg[e]; i0 = e; }
  int i1 = 0; float v1 = -1e30f;
  #pragma unroll
  for (int e = 0; e < 8; ++e) if (e != i0 && lg[e] > v1) { v1 = lg[e]; i1 = e; }
  float den = 0.0f; float pr[8];
  #pragma unroll
  for (int e = 0; e < 8; ++e) { pr[e] = __expf(lg[e] - v0); den += pr[e]; }
  const float dinv = 1.0f / den;
  float H = 0.0f, p0 = 0.0f, p1 = 0.0f;
  #pragma unroll
  for (int e = 0; e < 8; ++e) {
    const float p = pr[e] * dinv;
    H -= p * __logf(p + 1e-10f);
    if (e == i0) p0 = p;
    if (e == i1) p1 = p;
  }
  ent[token] = H;
  top2p[token * 2] = p0; top2p[token * 2 + 1] = p1;
  top2i[token * 2] = i0; top2i[token * 2 + 1] = i1;
  atomicAdd(&hist[i0], 1);
  atomicAdd(&hist[i1], 1);
  __syncthreads();
  if (t < 8) atomicAdd(&counts[t], hist[t]);
}

// scan: entropy mean (fixed order), offsets, aux, tile table
__global__ __launch_bounds__(256)
void scan_kernel(const float* __restrict__ ent, const int* __restrict__ counts,
                 int* __restrict__ offs, TileInfo* __restrict__ table, float* __restrict__ auxout) {
  __shared__ float red[256];
  const int t = threadIdx.x;
  float s = 0.0f;
  for (int k = 0; k < 32; ++k) s += ent[t + (k << 8)];
  red[t] = s; __syncthreads();
  for (int hh = 128; hh > 0; hh >>= 1) { if (t < hh) red[t] += red[t + hh]; __syncthreads(); }
  if (t == 0) {
    const float entmean = red[0] * (1.0f / 8192.0f);
    float pen = 0.0f; int off = 0; int nt = 0;
    for (int e = 0; e < 8; ++e) {
      const int c = counts[e];
      offs[e] = off;
      for (int m = 0; m < c; m += 128) {
        table[nt].m0 = off + m;
        table[nt].mcnt = (c - m < 128) ? (c - m) : 128;
        table[nt].e = e; table[nt].pad = 0;
        ++nt;
      }
      off += c;
      const float fr = (float)c * (1.0f / 8192.0f) - 0.3f;
      pen += (fr > 0.0f) ? fr : 0.0f;
    }
    for (; nt < 160; ++nt) { table[nt].m0 = 0; table[nt].mcnt = 0; table[nt].e = 0; table[nt].pad = 0; }
    auxout[0] = 0.1f * entmean + pen;
  }
}

// scatter: block-local LDS ranks + one chunk-reservation atomic per expert
__global__ __launch_bounds__(256)
void scatter_kernel(const int* __restrict__ top2i, const int* __restrict__ offs,
                    int* __restrict__ fill, int* __restrict__ moe_rows,
                    int* __restrict__ row2slot) {
  __shared__ int hist[8];
  __shared__ int base[8];
  const int t = threadIdx.x;
  if (t < 8) hist[t] = 0;
  __syncthreads();
  const int id = blockIdx.x * 256 + t;
  const int e = top2i[id];
  const int myrank = atomicAdd(&hist[e], 1);
  __syncthreads();
  if (t < 8) base[t] = atomicAdd(&fill[t], hist[t]);
  __syncthreads();
  const int row = offs[e] + base[e] + myrank;
  moe_rows[row] = id >> 1;
  row2slot[id] = row;
}

// x3 = x2 + p0*eo[r0] + p1*eo[r1]; also f16 copy for FF1
__global__ __launch_bounds__(256)
void combine_kernel(const float* __restrict__ x2, const f16* __restrict__ eo,
                    const float* __restrict__ top2p, const int* __restrict__ row2slot,
                    float* __restrict__ x3, f16* __restrict__ x3h) {
  const int n = blockIdx.x;
  const int t = threadIdx.x;
  const int r0 = row2slot[n * 2], r1 = row2slot[n * 2 + 1];
  const float p0 = top2p[n * 2], p1 = top2p[n * 2 + 1];
  const float4 xv = ((const float4*)(x2 + (size_t)n * 1024))[t];
  const f16x4 e0 = ((const f16x4*)(eo + (size_t)r0 * 1024))[t];
  const f16x4 e1 = ((const f16x4*)(eo + (size_t)r1 * 1024))[t];
  float4 o;
  o.x = xv.x + p0 * (float)e0[0] + p1 * (float)e1[0];
  o.y = xv.y + p0 * (float)e0[1] + p1 * (float)e1[1];
  o.z = xv.z + p0 * (float)e0[2] + p1 * (float)e1[2];
  o.w = xv.w + p0 * (float)e0[3] + p1 * (float)e1[3];
  ((float4*)(x3 + (size_t)n * 1024))[t] = o;
  f16x4 hv; hv[0] = (f16)o.x; hv[1] = (f16)o.y; hv[2] = (f16)o.z; hv[3] = (f16)o.w;
  ((f16x4*)(x3h + (size_t)n * 1024))[t] = hv;
}

// ---------------------------------------------------------------------------
extern "C" void kernel_launch(void* const* d_in, const int* in_sizes, int n_in,
                              void* d_out, int out_size, void* d_ws, size_t ws_size,
                              hipStream_t stream) {
  (void)in_sizes; (void)n_in; (void)out_size; (void)ws_size;
  const float* x     = (const float*)d_in[0];
  const float* g1    = (const float*)d_in[1];
  const float* b1    = (const float*)d_in[2];
  const float* g2    = (const float*)d_in[3];
  const float* b2    = (const float*)d_in[4];
  const float* g3    = (const float*)d_in[5];
  const float* b3    = (const float*)d_in[6];
  const float* Wqkv  = (const float*)d_in[7];
  const float* bqkv  = (const float*)d_in[8];
  const float* Wo    = (const float*)d_in[9];
  const float* bo    = (const float*)d_in[10];
  const float* convw = (const float*)d_in[11];
  const float* convb = (const float*)d_in[12];
  const float* gateW = (const float*)d_in[13];
  const float* gateb = (const float*)d_in[14];
  const float* expW  = (const float*)d_in[15];
  const float* expb  = (const float*)d_in[16];
  const float* ffW1  = (const float*)d_in[17];
  const float* ffb1  = (const float*)d_in[18];
  const float* ffW2  = (const float*)d_in[19];
  const float* ffb2  = (const float*)d_in[20];
  float* out = (float*)d_out;

  char* W = (char*)d_ws;
  f16* wqkvT_h = (f16*)(W + 0);
  f16* wqkvT_l = (f16*)(W + 6291456);
  f16* woT_h   = (f16*)(W + 12582912);
  f16* woT_l   = (f16*)(W + 14680064);
  f16* wcvT_h  = (f16*)(W + 16777216);
  f16* wcvT_l  = (f16*)(W + 23068672);
  f16* wexpT   = (f16*)(W + 29360128);
  f16* wff1T   = (f16*)(W + 46137344);
  f16* wff2T   = (f16*)(W + 54525952);
  char* META   = W + 62914560;
  int* counts    = (int*)(META);
  int* fill      = (int*)(META + 32);
  int* offs      = (int*)(META + 64);
  TileInfo* table = (TileInfo*)(META + 128);
  char* zbuf     = META + 3072;
  float* ent     = (float*)(META + 24576);
  float* top2p   = (float*)(META + 57344);
  int* top2i     = (int*)(META + 122880);
  int* moe_rows  = (int*)(META + 188416);
  int* row2slot  = (int*)(META + 253952);
  float* logits  = (float*)(META + 327680);
  char* SA = W + 63963136;
  char* SB = W + 97517568;
  char* SC = W + 164626432;
  char* SD = W + 198180864;
  char* SE = W + 231735296;

  f16* ln1h = (f16*)SA;            f16* ln1l = (f16*)(SA + 16777216);
  f16* ln2h = ln1h;                f16* ln2l = ln1l;
  f16* ln3h = ln1h;                f16* x3h  = (f16*)(SA + 16777216);
  float* qkvbuf = (float*)SB;
  float* x2buf  = (float*)SB;
  f16*   hbuf   = (f16*)SB;
  f16* attnh = (f16*)SC;           f16* attnl = (f16*)(SC + 16777216);
  float* x1 = (float*)SD;
  f16* eobuf = (f16*)SD;
  float* x3 = (float*)SE;

  hipMemsetAsync((void*)META, 0, 4096, stream);

  dim3 blk(256);
  // weight prep
  transpose_kernel<1><<<dim3(96, 32, 1), blk, 0, stream>>>(Wqkv, 1024, 3072, wqkvT_h, wqkvT_l);
  transpose_kernel<1><<<dim3(32, 32, 1), blk, 0, stream>>>(Wo, 1024, 1024, woT_h, woT_l);
  convw_kernel<<<4096, blk, 0, stream>>>(convw, wcvT_h, wcvT_l);
  transpose_kernel<0><<<dim3(32, 32, 8), blk, 0, stream>>>(expW, 1024, 1024, wexpT, nullptr);
  transpose_kernel<0><<<dim3(128, 32, 1), blk, 0, stream>>>(ffW1, 1024, 4096, wff1T, nullptr);
  transpose_kernel<0><<<dim3(32, 128, 1), blk, 0, stream>>>(ffW2, 4096, 1024, wff2T, nullptr);

  // LN1 -> split planes, COMPACT (only the 4352 rows attention consumes)
  ln_kernel<1, 0, 1><<<4352, blk, 0, stream>>>(x, g1, b1, ln1h, ln1l, nullptr, nullptr, nullptr);
  // QKV on compact rows, split GEMM, fp32 out
  gemm_kernel<3, 0, 0><<<dim3(34, 24), blk, 0, stream>>>(ln1h, ln1l, 1024, wqkvT_h, wqkvT_l, 1024,
      bqkv, nullptr, qkvbuf, nullptr, 3072, 1024, nullptr, nullptr, nullptr);
  // attention (512 threads)
  attn_kernel<<<512, dim3(512), 0, stream>>>(qkvbuf, attnh, attnl);
  // Wo projection + residual -> x1
  gemm_kernel<3, 0, 1><<<dim3(64, 8), blk, 0, stream>>>(attnh, attnl, 1024, woT_h, woT_l, 1024,
      bo, x, x1, nullptr, 1024, 1024, nullptr, nullptr, nullptr);
  // LN2
  ln_kernel<1, 0, 0><<<8192, blk, 0, stream>>>(x1, g2, b2, ln2h, ln2l, nullptr, nullptr, nullptr);
  // conv (3-tap shifted GEMM, exact zero-pad) + residual -> x2
  gemm_kernel<3, 3, 1><<<dim3(64, 8), blk, 0, stream>>>(ln2h, ln2l, 1024, wcvT_h, wcvT_l, 3072,
      convb, x1, x2buf, nullptr, 1024, 3072, nullptr, nullptr, zbuf);
  // LN3 fused with gate logits
  ln_kernel<0, 1, 0><<<8192, blk, 0, stream>>>(x2buf, g3, b3, ln3h, nullptr, gateW, gateb, logits);
  // gate finalize / scan / scatter
  gatefin_kernel<<<32, blk, 0, stream>>>(logits, top2p, top2i, ent, counts);
  scan_kernel<<<1, blk, 0, stream>>>(ent, counts, offs, table, out + 8388608);
  scatter_kernel<<<64, blk, 0, stream>>>(top2i, offs, fill, moe_rows, row2slot);
  // grouped expert GEMM -> eo (f16)
  gemm_kernel<1, 2, 2><<<dim3(136, 8), blk, 0, stream>>>(ln3h, nullptr, 1024, wexpT, nullptr, 1024,
      expb, nullptr, nullptr, eobuf, 1024, 1024, moe_rows, table, nullptr);
  // combine -> x3 (+f16)
  combine_kernel<<<8192, blk, 0, stream>>>(x2buf, eobuf, top2p, row2slot, x3, x3h);
  // FF1 (gelu) -> h
  gemm_kernel<1, 0, 3><<<dim3(64, 32), blk, 0, stream>>>(x3h, nullptr, 1024, wff1T, nullptr, 1024,
      ffb1, nullptr, nullptr, hbuf, 4096, 1024, nullptr, nullptr, nullptr);
  // FF2 + residual -> final output
  gemm_kernel<1, 0, 1><<<dim3(64, 8), blk, 0, stream>>>(hbuf, nullptr, 4096, wff2T, nullptr, 4096,
      ffb2, x3, out, nullptr, 1024, 4096, nullptr, nullptr, nullptr);
}

// Round 11
// 743.898 us; speedup vs baseline: 1.0572x; 1.0572x over previous
//
#include <hip/hip_runtime.h>
#include <cmath>

typedef _Float16 f16;
typedef __attribute__((ext_vector_type(8))) _Float16 f16x8;
typedef __attribute__((ext_vector_type(4))) _Float16 f16x4;
typedef __attribute__((ext_vector_type(4))) float f32x4;

struct TileInfo { int m0, mcnt, e, pad; };

__device__ __forceinline__ void gload16(const void* g, void* l) {
  __builtin_amdgcn_global_load_lds((const __attribute__((address_space(1))) void*)g,
                                   (__attribute__((address_space(3))) void*)l, 16, 0, 0);
}

// fast gelu: 0.5u(1+tanh(c)) = u*e/(e+1), e=exp(2c), c=0.79788456(u+0.044715u^3)
__device__ __forceinline__ float fast_gelu(float u) {
  const float c = u * (0.7978845608028654f + 0.0356774081f * u * u);
  const float t = fminf(2.0f * c, 80.0f);
  const float e = __expf(t);
  return u * (e * __builtin_amdgcn_rcpf(e + 1.0f));
}

// ---------------------------------------------------------------------------
// Unified GEMM (R7-proven; default block mapping — measured traffic-optimal).
//   NPASS==1: BK=64, LDS double-buffer (2x32KB), counted vmcnt(8).
//   NPASS==3: BK=64, single 64KB buffer (Ah/Al/Bh/Bl planes).
// MODE: 0 direct, 1 rowmap, 2 tile-table (MoE), 3 conv (zero-pad via zbuf).
// EPI: 0 f32=acc+bias; 1 f32=res+acc+bias; 2 f16=acc+bias; 3 f16=gelu(acc+bias)
// ---------------------------------------------------------------------------
template<int NPASS, int MODE, int EPI>
__global__ __launch_bounds__(256)
void gemm_kernel(const f16* __restrict__ Ah, const f16* __restrict__ Al, int lda,
                 const f16* __restrict__ Bh, const f16* __restrict__ Bl, int ldb,
                 const float* __restrict__ bias, const float* __restrict__ res,
                 float* __restrict__ outf, f16* __restrict__ outh, int ldo, int K,
                 const int* __restrict__ rowmap, const TileInfo* __restrict__ table,
                 const char* __restrict__ zbuf) {
  __shared__ __align__(16) char lds[65536];

  const int tid  = threadIdx.x;
  const int wave = tid >> 6;
  const int lane = tid & 63;

  int m0, mcnt, eidx = 0;
  if (MODE == 2) {
    TileInfo ti = table[blockIdx.x];
    if (ti.mcnt <= 0) return;
    m0 = ti.m0; mcnt = ti.mcnt; eidx = ti.e;
  } else { m0 = blockIdx.x * 128; mcnt = 128; }
  const int n0 = blockIdx.y * 128;

  const f16* Bh_ = Bh;
  const float* bias_ = bias;
  size_t adelta = 0, bdelta = 0;
  if (NPASS == 3) {
    adelta = (size_t)((const char*)Al - (const char*)Ah);
    bdelta = (size_t)((const char*)Bl - (const char*)Bh);
  }
  if (MODE == 2) { Bh_ += ((size_t)eidx << 20); bias_ += eidx * 1024; }

  f32x4 acc[4][4] = {};
  const int wm  = (wave >> 1) * 64;
  const int wn  = (wave & 1) * 64;
  const int fr  = lane & 15;
  const int kgb = (lane >> 4) * 16;
  const int wuni = wave * 1024;

  const int sr    = tid / 8;          // 0..31
  const int cbyte = (tid % 8) * 16;

  if constexpr (NPASS == 1) {
    // ---- BK=64 double-buffered counted-vmcnt (R7, proven) ----
    const char* aSrc[4];
    const char* bSrc[4];
    #pragma unroll
    for (int r = 0; r < 4; ++r) {
      const int mr  = sr + r * 32;
      const int cbs = cbyte ^ ((mr & 7) << 4);
      int gi = m0 + ((mr < mcnt) ? mr : (mcnt - 1));
      if (MODE == 1 || MODE == 2) gi = rowmap[gi];
      aSrc[r] = (const char*)Ah + (size_t)gi * lda * 2 + cbs;
      bSrc[r] = (const char*)Bh_ + (size_t)(n0 + mr) * ldb * 2 + cbs;
    }
    const int NT = K / 64;
    #pragma unroll
    for (int r = 0; r < 4; ++r) {
      gload16(aSrc[r], lds + r * 4096 + wuni);
      gload16(bSrc[r], lds + 16384 + r * 4096 + wuni);
    }
    #pragma unroll
    for (int r = 0; r < 4; ++r) {
      gload16(aSrc[r] + 128, lds + 32768 + r * 4096 + wuni);
      gload16(bSrc[r] + 128, lds + 32768 + 16384 + r * 4096 + wuni);
    }
    asm volatile("s_waitcnt vmcnt(8)" ::: "memory");
    __builtin_amdgcn_s_barrier();

    for (int kt = 0; kt < NT; ++kt) {
      const int c = kt & 1;
      const char* LAp = lds + c * 32768;
      const char* LBp = LAp + 16384;
      f16x8 ah[2][4], bh[2][4];
      #pragma unroll
      for (int kk = 0; kk < 2; ++kk) {
        #pragma unroll
        for (int i = 0; i < 4; ++i) {
          const int ar = wm + i * 16 + fr;
          ah[kk][i] = *(const f16x8*)(LAp + ar * 128 + ((kk * 64 + kgb) ^ ((ar & 7) << 4)));
          const int br = wn + i * 16 + fr;
          bh[kk][i] = *(const f16x8*)(LBp + br * 128 + ((kk * 64 + kgb) ^ ((br & 7) << 4)));
        }
      }
      asm volatile("s_waitcnt lgkmcnt(0)" ::: "memory");
      __builtin_amdgcn_s_barrier();
      if (kt + 2 < NT) {
        const size_t ko = (size_t)(kt + 2) * 128;
        #pragma unroll
        for (int r = 0; r < 4; ++r) {
          gload16(aSrc[r] + ko, lds + c * 32768 + r * 4096 + wuni);
          gload16(bSrc[r] + ko, lds + c * 32768 + 16384 + r * 4096 + wuni);
        }
      }
      #pragma unroll
      for (int kk = 0; kk < 2; ++kk)
        #pragma unroll
        for (int i = 0; i < 4; ++i)
          #pragma unroll
          for (int j = 0; j < 4; ++j)
            acc[i][j] = __builtin_amdgcn_mfma_f32_16x16x32_f16(ah[kk][i], bh[kk][j], acc[i][j], 0, 0, 0);
      if (kt + 2 < NT) asm volatile("s_waitcnt vmcnt(8)" ::: "memory");
      else             asm volatile("s_waitcnt vmcnt(0)" ::: "memory");
      __builtin_amdgcn_s_barrier();
    }
  } else {
    // ---- NPASS==3: single-buffered 3-pass loop (R7, proven) ----
    const char* aSrcB[4]; const char* bSrcB[4];
    int aRowC[4], aCbs[4];
    #pragma unroll
    for (int r = 0; r < 4; ++r) {
      const int mr  = sr + r * 32;
      const int cbs = cbyte ^ ((mr & 7) << 4);
      int gi = m0 + mr;
      if (MODE == 1) gi = rowmap[gi];
      if (MODE == 3) { aRowC[r] = gi; aCbs[r] = cbs; aSrcB[r] = nullptr; }
      else           { aSrcB[r] = (const char*)Ah + (size_t)gi * lda * 2 + cbs; aRowC[r] = 0; aCbs[r] = 0; }
      bSrcB[r] = (const char*)Bh_ + (size_t)(n0 + mr) * ldb * 2 + cbs;
    }
    for (int k0 = 0; k0 < K; k0 += 64) {
      #pragma unroll
      for (int r = 0; r < 4; ++r) {
        const char* as; const char* asl;
        if (MODE == 3) {
          const int tap = k0 >> 10;
          const int kc  = k0 & 1023;
          const int tok = aRowC[r] & 4095;
          const int stk = tok + (tap - 1) * 2;
          if (stk >= 0 && stk < 4096) {
            as  = (const char*)Ah + (size_t)(aRowC[r] + (tap - 1) * 2) * 2048 + kc * 2 + aCbs[r];
            asl = as + adelta;
          } else { as = zbuf; asl = zbuf; }
        } else {
          as  = aSrcB[r] + (size_t)k0 * 2;
          asl = as + adelta;
        }
        gload16(as,  lds + 0     + r * 4096 + wuni);
        gload16(asl, lds + 16384 + r * 4096 + wuni);
        const char* bs = bSrcB[r] + (size_t)k0 * 2;
        gload16(bs,          lds + 32768 + r * 4096 + wuni);
        gload16(bs + bdelta, lds + 49152 + r * 4096 + wuni);
      }
      __syncthreads();
      #pragma unroll
      for (int kk = 0; kk < 2; ++kk) {
        f16x8 ah[4], al[4], bh[4], bl[4];
        #pragma unroll
        for (int i = 0; i < 4; ++i) {
          const int ar = wm + i * 16 + fr;
          const int ao = ar * 128 + ((kk * 64 + kgb) ^ ((ar & 7) << 4));
          ah[i] = *(const f16x8*)(lds + ao);
          al[i] = *(const f16x8*)(lds + 16384 + ao);
          const int br = wn + i * 16 + fr;
          const int bo = br * 128 + ((kk * 64 + kgb) ^ ((br & 7) << 4));
          bh[i] = *(const f16x8*)(lds + 32768 + bo);
          bl[i] = *(const f16x8*)(lds + 49152 + bo);
        }
        #pragma unroll
        for (int i = 0; i < 4; ++i) {
          #pragma unroll
          for (int j = 0; j < 4; ++j) {
            acc[i][j] = __builtin_amdgcn_mfma_f32_16x16x32_f16(ah[i], bh[j], acc[i][j], 0, 0, 0);
            acc[i][j] = __builtin_amdgcn_mfma_f32_16x16x32_f16(ah[i], bl[j], acc[i][j], 0, 0, 0);
            acc[i][j] = __builtin_amdgcn_mfma_f32_16x16x32_f16(al[i], bh[j], acc[i][j], 0, 0, 0);
          }
        }
      }
      __syncthreads();
    }
  }

  #pragma unroll
  for (int i = 0; i < 4; ++i) {
    const int mb = wm + i * 16 + (lane >> 4) * 4;
    #pragma unroll
    for (int j = 0; j < 4; ++j) {
      const int nc = n0 + wn + j * 16 + fr;
      const float bv = bias_[nc];
      #pragma unroll
      for (int q = 0; q < 4; ++q) {
        const int ml = mb + q;
        if (MODE == 2 && ml >= mcnt) continue;
        const size_t orow = (size_t)(m0 + ml);
        float v = acc[i][j][q] + bv;
        if (EPI == 1) v += res[orow * ldo + nc];
        if (EPI == 3) v = fast_gelu(v);
        if (EPI <= 1) outf[orow * ldo + nc] = v;
        else          outh[orow * ldo + nc] = (f16)v;
      }
    }
  }
}

// ---------------------------------------------------------------------------
// LayerNorm: fp32 in -> f16 hi (+optional lo plane). WGATE: fused gate logits.
// COMPACT: read source row (row<2176 ? row : row+1920), write compact row.
// ---------------------------------------------------------------------------
template<int WLO, int WGATE, int COMPACT>
__global__ __launch_bounds__(256)
void ln_kernel(const float* __restrict__ x, const float* __restrict__ g, const float* __restrict__ b,
               f16* __restrict__ oh, f16* __restrict__ ol,
               const float* __restrict__ gW, const float* __restrict__ gb,
               float* __restrict__ logits) {
  const int row = blockIdx.x;
  const int srow = COMPACT ? ((row < 2176) ? row : row + 1920) : row;
  const int t = threadIdx.x;
  const float4 v = ((const float4*)(x + (size_t)srow * 1024))[t];
  float s  = v.x + v.y + v.z + v.w;
  float ss = v.x * v.x + v.y * v.y + v.z * v.z + v.w * v.w;
  #pragma unroll
  for (int off = 32; off; off >>= 1) { s += __shfl_down(s, off, 64); ss += __shfl_down(ss, off, 64); }
  __shared__ float red[8];
  if ((t & 63) == 0) { red[t >> 6] = s; red[(t >> 6) + 4] = ss; }
  __syncthreads();
  s  = red[0] + red[1] + red[2] + red[3];
  ss = red[4] + red[5] + red[6] + red[7];
  const float mu  = s * (1.0f / 1024.0f);
  const float var = ss * (1.0f / 1024.0f) - mu * mu;
  const float inv = 1.0f / sqrtf(var + 1e-5f);
  const float4 gv = ((const float4*)g)[t];
  const float4 bv = ((const float4*)b)[t];
  float y[4];
  y[0] = (v.x - mu) * inv * gv.x + bv.x;
  y[1] = (v.y - mu) * inv * gv.y + bv.y;
  y[2] = (v.z - mu) * inv * gv.z + bv.z;
  y[3] = (v.w - mu) * inv * gv.w + bv.w;
  f16x4 hv;
  #pragma unroll
  for (int u = 0; u < 4; ++u) hv[u] = (f16)y[u];
  *(f16x4*)(oh + (size_t)row * 1024 + t * 4) = hv;
  if (WLO) {
    f16x4 lv;
    #pragma unroll
    for (int u = 0; u < 4; ++u) lv[u] = (f16)(y[u] - (float)hv[u]);
    *(f16x4*)(ol + (size_t)row * 1024 + t * 4) = lv;
  }
  if (WGATE) {
    const float* gr = gW + (size_t)(t * 4) * 8;
    float lg[8];
    #pragma unroll
    for (int e = 0; e < 8; ++e)
      lg[e] = y[0] * gr[e] + y[1] * gr[8 + e] + y[2] * gr[16 + e] + y[3] * gr[24 + e];
    #pragma unroll
    for (int m = 1; m < 64; m <<= 1)
      #pragma unroll
      for (int e = 0; e < 8; ++e) lg[e] += __shfl_xor(lg[e], m, 64);
    __shared__ float gred[4][8];
    if ((t & 63) == 0) {
      #pragma unroll
      for (int e = 0; e < 8; ++e) gred[t >> 6][e] = lg[e];
    }
    __syncthreads();
    if (t < 8)
      logits[(size_t)row * 8 + t] = gred[0][t] + gred[1][t] + gred[2][t] + gred[3][t] + gb[t];
  }
}

// ---------------------------------------------------------------------------
// Windowed attention (512 thr/block): see R6.
// ---------------------------------------------------------------------------
__global__ __launch_bounds__(512, 4)
void attn_kernel(const float* __restrict__ qkv, f16* __restrict__ oh, f16* __restrict__ ol) {
  __shared__ __align__(16) char sm[81920];
  const int bid = blockIdx.x;
  const int b = bid >> 8, h = (bid >> 4) & 15, n = bid & 15;
  const int t = threadIdx.x;
  const size_t rowbase = (size_t)(b * 2176 + n * 128);
  const char* qg = (const char*)(qkv + rowbase * 3072 + h * 64);
  const char* kg = qg + 4096;
  const char* vg = qg + 8192;

  const int srow = t >> 4;
  const int scol = (t & 15) * 16;
  const int wuni = (t >> 6) * 1024;

  const int dt = t >> 4;
  const int et = t & 15;
  float pacc[2][4] = {};

  for (int r = 0; r < 2; ++r) {
    #pragma unroll
    for (int p = 0; p < 4; ++p) {
      const size_t off = (size_t)(r * 128 + p * 32 + srow) * 12288 + scol;
      gload16(qg + off, sm + p * 8192 + wuni);
      gload16(kg + off, sm + 32768 + p * 8192 + wuni);
    }
    __syncthreads();
    #pragma unroll 4
    for (int s = 0; s < 128; ++s) {
      const float2 q2 = *(const float2*)(sm + s * 256 + dt * 8);
      const f32x4 k4 = *(const f32x4*)(sm + 32768 + s * 256 + et * 16);
      #pragma unroll
      for (int z = 0; z < 4; ++z) {
        pacc[0][z] += q2.x * k4[z];
        pacc[1][z] += q2.y * k4[z];
      }
    }
    __syncthreads();
  }

  #pragma unroll
  for (int i = 0; i < 2; ++i) {
    #pragma unroll
    for (int z = 0; z < 4; ++z) pacc[i][z] *= 0.125f;
    float m = fmaxf(fmaxf(pacc[i][0], pacc[i][1]), fmaxf(pacc[i][2], pacc[i][3]));
    m = fmaxf(m, __shfl_xor(m, 1, 16));
    m = fmaxf(m, __shfl_xor(m, 2, 16));
    m = fmaxf(m, __shfl_xor(m, 4, 16));
    m = fmaxf(m, __shfl_xor(m, 8, 16));
    float den = 0.0f;
    #pragma unroll
    for (int z = 0; z < 4; ++z) { pacc[i][z] = __expf(pacc[i][z] - m); den += pacc[i][z]; }
    den += __shfl_xor(den, 1, 16);
    den += __shfl_xor(den, 2, 16);
    den += __shfl_xor(den, 4, 16);
    den += __shfl_xor(den, 8, 16);
    const float dinv = 1.0f / den;
    f32x4 pv;
    #pragma unroll
    for (int z = 0; z < 4; ++z) pv[z] = pacc[i][z] * dinv;
    *(f32x4*)(sm + 65536 + (dt * 2 + i) * 256 + et * 16) = pv;
  }

  const int dt2 = t & 15;
  const int st  = t >> 4;
  const int ch  = h * 64 + (st & 15) * 4;
  const size_t rb2 = (size_t)(b * 4096 + n * 256);

  for (int c = 0; c < 2; ++c) {
    __syncthreads();
    #pragma unroll
    for (int p = 0; p < 4; ++p) {
      const size_t off = (size_t)(c * 128 + p * 32 + srow) * 12288 + scol;
      gload16(vg + off, sm + p * 8192 + wuni);
    }
    __syncthreads();
    float o[16];
    #pragma unroll
    for (int u = 0; u < 16; ++u) o[u] = 0.0f;
    #pragma unroll 2
    for (int e4 = 0; e4 < 16; ++e4) {
      f32x4 p4[4], v4[4];
      #pragma unroll
      for (int i = 0; i < 4; ++i)
        p4[i] = *(const f32x4*)(sm + 65536 + (dt2 * 4 + i) * 256 + e4 * 16);
      #pragma unroll
      for (int j = 0; j < 4; ++j)
        v4[j] = *(const f32x4*)(sm + (st * 4 + j) * 256 + e4 * 16);
      #pragma unroll
      for (int j = 0; j < 4; ++j)
        #pragma unroll
        for (int i = 0; i < 4; ++i) {
          o[j * 4 + i] += v4[j][0] * p4[i][0] + v4[j][1] * p4[i][1]
                        + v4[j][2] * p4[i][2] + v4[j][3] * p4[i][3];
        }
    }
    const int rq = c * 2 + (st >> 4);
    #pragma unroll
    for (int i = 0; i < 4; ++i) {
      const size_t row = rb2 + (size_t)(dt2 * 4 + i) * 4 + rq;
      f16x4 hv, lv;
      #pragma unroll
      for (int j = 0; j < 4; ++j) {
        const float val = o[j * 4 + i];
        hv[j] = (f16)val;
        lv[j] = (f16)(val - (float)hv[j]);
      }
      *(f16x4*)(oh + row * 1024 + ch) = hv;
      *(f16x4*)(ol + row * 1024 + ch) = lv;
    }
  }
}

// ---------------------------------------------------------------------------
// weight transposes fp32 -> f16 (optional lo plane); batched over blockIdx.z
// ---------------------------------------------------------------------------
template<int SPLIT>
__global__ __launch_bounds__(256)
void transpose_kernel(const float* __restrict__ in, int R, int Cc,
                      f16* __restrict__ oh, f16* __restrict__ ol) {
  __shared__ float tile[32][33];
  const size_t mat = (size_t)blockIdx.z * R * Cc;
  in += mat; oh += mat; if (SPLIT) ol += mat;
  const int tx = threadIdx.x & 31, ty = threadIdx.x >> 5;
  const int c = blockIdx.x * 32 + tx;
  #pragma unroll
  for (int j = 0; j < 32; j += 8) {
    const int r = blockIdx.y * 32 + ty + j;
    tile[ty + j][tx] = in[(size_t)r * Cc + c];
  }
  __syncthreads();
  const int rT = blockIdx.y * 32 + tx;
  #pragma unroll
  for (int j = 0; j < 32; j += 8) {
    const int cT = blockIdx.x * 32 + ty + j;
    const float v = tile[tx][ty + j];
    const f16 hv = (f16)v;
    oh[(size_t)cT * R + rT] = hv;
    if (SPLIT) ol[(size_t)cT * R + rT] = (f16)(v - (float)hv);
  }
}

// conv weights [O,I,3] -> BT[o][tap*1024+i] hi/lo
__global__ __launch_bounds__(256)
void convw_kernel(const float* __restrict__ w, f16* __restrict__ oh, f16* __restrict__ ol) {
  const int id = blockIdx.x * 256 + threadIdx.x;
  const int o = id >> 10, i = id & 1023;
  const float* ws = w + (size_t)o * 3072 + i * 3;
  #pragma unroll
  for (int tap = 0; tap < 3; ++tap) {
    const float v = ws[tap];
    const f16 hv = (f16)v;
    const size_t oi = (size_t)o * 3072 + tap * 1024 + i;
    oh[oi] = hv;
    ol[oi] = (f16)(v - (float)hv);
  }
}

// ---------------------------------------------------------------------------
// gate finalize
// ---------------------------------------------------------------------------
__global__ __launch_bounds__(256)
void gatefin_kernel(const float* __restrict__ logits, float* __restrict__ top2p,
                    int* __restrict__ top2i, float* __restrict__ ent,
                    int* __restrict__ counts) {
  __shared__ int hist[8];
  const int t = threadIdx.x;
  if (t < 8) hist[t] = 0;
  __syncthreads();
  const int token = blockIdx.x * 256 + t;
  float lg[8];
  const float4 l0 = ((const float4*)(logits + (size_t)token * 8))[0];
  const float4 l1 = ((const float4*)(logits + (size_t)token * 8))[1];
  lg[0] = l0.x; lg[1] = l0.y; lg[2] = l0.z; lg[3] = l0.w;
  lg[4] = l1.x; lg[5] = l1.y; lg[6] = l1.z; lg[7] = l1.w;
  int i0 = 0; float v0 = lg[0];
  #pragma unroll
  for (int e = 1; e < 8; ++e) if (lg[e] > v0) { v0 = lg[e]; i0 = e; }
  int i1 = 0; float v1 = -1e30f;
  #pragma unroll
  for (int e = 0; e < 8; ++e) if (e != i0 && lg[e] > v1) { v1 = lg[e]; i1 = e; }
  float den = 0.0f; float pr[8];
  #pragma unroll
  for (int e = 0; e < 8; ++e) { pr[e] = __expf(lg[e] - v0); den += pr[e]; }
  const float dinv = 1.0f / den;
  float H = 0.0f, p0 = 0.0f, p1 = 0.0f;
  #pragma unroll
  for (int e = 0; e < 8; ++e) {
    const float p = pr[e] * dinv;
    H -= p * __logf(p + 1e-10f);
    if (e == i0) p0 = p;
    if (e == i1) p1 = p;
  }
  ent[token] = H;
  top2p[token * 2] = p0; top2p[token * 2 + 1] = p1;
  top2i[token * 2] = i0; top2i[token * 2 + 1] = i1;
  atomicAdd(&hist[i0], 1);
  atomicAdd(&hist[i1], 1);
  __syncthreads();
  if (t < 8) atomicAdd(&counts[t], hist[t]);
}

// scan: entropy mean (fixed order), offsets, aux, tile table
__global__ __launch_bounds__(256)
void scan_kernel(const float* __restrict__ ent, const int* __restrict__ counts,
                 int* __restrict__ offs, TileInfo* __restrict__ table, float* __restrict__ auxout) {
  __shared__ float red[256];
  const int t = threadIdx.x;
  float s = 0.0f;
  for (int k = 0; k < 32; ++k) s += ent[t + (k << 8)];
  red[t] = s; __syncthreads();
  for (int hh = 128; hh > 0; hh >>= 1) { if (t < hh) red[t] += red[t + hh]; __syncthreads(); }
  if (t == 0) {
    const float entmean = red[0] * (1.0f / 8192.0f);
    float pen = 0.0f; int off = 0; int nt = 0;
    for (int e = 0; e < 8; ++e) {
      const int c = counts[e];
      offs[e] = off;
      for (int m = 0; m < c; m += 128) {
        table[nt].m0 = off + m;
        table[nt].mcnt = (c - m < 128) ? (c - m) : 128;
        table[nt].e = e; table[nt].pad = 0;
        ++nt;
      }
      off += c;
      const float fr = (float)c * (1.0f / 8192.0f) - 0.3f;
      pen += (fr > 0.0f) ? fr : 0.0f;
    }
    for (; nt < 160; ++nt) { table[nt].m0 = 0; table[nt].mcnt = 0; table[nt].e = 0; table[nt].pad = 0; }
    auxout[0] = 0.1f * entmean + pen;
  }
}

// scatter: block-local LDS ranks + one chunk-reservation atomic per expert
__global__ __launch_bounds__(256)
void scatter_kernel(const int* __restrict__ top2i, const int* __restrict__ offs,
                    int* __restrict__ fill, int* __restrict__ moe_rows,
                    int* __restrict__ row2slot) {
  __shared__ int hist[8];
  __shared__ int base[8];
  const int t = threadIdx.x;
  if (t < 8) hist[t] = 0;
  __syncthreads();
  const int id = blockIdx.x * 256 + t;
  const int e = top2i[id];
  const int myrank = atomicAdd(&hist[e], 1);
  __syncthreads();
  if (t < 8) base[t] = atomicAdd(&fill[t], hist[t]);
  __syncthreads();
  const int row = offs[e] + base[e] + myrank;
  moe_rows[row] = id >> 1;
  row2slot[id] = row;
}

// x3 = x2 + p0*eo[r0] + p1*eo[r1]; also f16 copy for FF1
__global__ __launch_bounds__(256)
void combine_kernel(const float* __restrict__ x2, const f16* __restrict__ eo,
                    const float* __restrict__ top2p, const int* __restrict__ row2slot,
                    float* __restrict__ x3, f16* __restrict__ x3h) {
  const int n = blockIdx.x;
  const int t = threadIdx.x;
  const int r0 = row2slot[n * 2], r1 = row2slot[n * 2 + 1];
  const float p0 = top2p[n * 2], p1 = top2p[n * 2 + 1];
  const float4 xv = ((const float4*)(x2 + (size_t)n * 1024))[t];
  const f16x4 e0 = ((const f16x4*)(eo + (size_t)r0 * 1024))[t];
  const f16x4 e1 = ((const f16x4*)(eo + (size_t)r1 * 1024))[t];
  float4 o;
  o.x = xv.x + p0 * (float)e0[0] + p1 * (float)e1[0];
  o.y = xv.y + p0 * (float)e0[1] + p1 * (float)e1[1];
  o.z = xv.z + p0 * (float)e0[2] + p1 * (float)e1[2];
  o.w = xv.w + p0 * (float)e0[3] + p1 * (float)e1[3];
  ((float4*)(x3 + (size_t)n * 1024))[t] = o;
  f16x4 hv; hv[0] = (f16)o.x; hv[1] = (f16)o.y; hv[2] = (f16)o.z; hv[3] = (f16)o.w;
  ((f16x4*)(x3h + (size_t)n * 1024))[t] = hv;
}

// ---------------------------------------------------------------------------
extern "C" void kernel_launch(void* const* d_in, const int* in_sizes, int n_in,
                              void* d_out, int out_size, void* d_ws, size_t ws_size,
                              hipStream_t stream) {
  (void)in_sizes; (void)n_in; (void)out_size; (void)ws_size;
  const float* x     = (const float*)d_in[0];
  const float* g1    = (const float*)d_in[1];
  const float* b1    = (const float*)d_in[2];
  const float* g2    = (const float*)d_in[3];
  const float* b2    = (const float*)d_in[4];
  const float* g3    = (const float*)d_in[5];
  const float* b3    = (const float*)d_in[6];
  const float* Wqkv  = (const float*)d_in[7];
  const float* bqkv  = (const float*)d_in[8];
  const float* Wo    = (const float*)d_in[9];
  const float* bo    = (const float*)d_in[10];
  const float* convw = (const float*)d_in[11];
  const float* convb = (const float*)d_in[12];
  const float* gateW = (const float*)d_in[13];
  const float* gateb = (const float*)d_in[14];
  const float* expW  = (const float*)d_in[15];
  const float* expb  = (const float*)d_in[16];
  const float* ffW1  = (const float*)d_in[17];
  const float* ffb1  = (const float*)d_in[18];
  const float* ffW2  = (const float*)d_in[19];
  const float* ffb2  = (const float*)d_in[20];
  float* out = (float*)d_out;

  char* W = (char*)d_ws;
  f16* wqkvT_h = (f16*)(W + 0);
  f16* wqkvT_l = (f16*)(W + 6291456);
  f16* woT_h   = (f16*)(W + 12582912);
  f16* woT_l   = (f16*)(W + 14680064);
  f16* wcvT_h  = (f16*)(W + 16777216);
  f16* wcvT_l  = (f16*)(W + 23068672);
  f16* wexpT   = (f16*)(W + 29360128);
  f16* wff1T   = (f16*)(W + 46137344);
  f16* wff2T   = (f16*)(W + 54525952);
  char* META   = W + 62914560;
  int* counts    = (int*)(META);
  int* fill      = (int*)(META + 32);
  int* offs      = (int*)(META + 64);
  TileInfo* table = (TileInfo*)(META + 128);
  char* zbuf     = META + 3072;
  float* ent     = (float*)(META + 24576);
  float* top2p   = (float*)(META + 57344);
  int* top2i     = (int*)(META + 122880);
  int* moe_rows  = (int*)(META + 188416);
  int* row2slot  = (int*)(META + 253952);
  float* logits  = (float*)(META + 327680);
  char* SA = W + 63963136;
  char* SB = W + 97517568;
  char* SC = W + 164626432;
  char* SD = W + 198180864;
  char* SE = W + 231735296;

  f16* ln1h = (f16*)SA;            f16* ln1l = (f16*)(SA + 16777216);
  f16* ln2h = ln1h;                f16* ln2l = ln1l;
  f16* ln3h = ln1h;                f16* x3h  = (f16*)(SA + 16777216);
  float* qkvbuf = (float*)SB;
  float* x2buf  = (float*)SB;
  f16*   hbuf   = (f16*)SB;
  f16* attnh = (f16*)SC;           f16* attnl = (f16*)(SC + 16777216);
  float* x1 = (float*)SD;
  f16* eobuf = (f16*)SD;
  float* x3 = (float*)SE;

  hipMemsetAsync((void*)META, 0, 4096, stream);

  dim3 blk(256);
  // weight prep
  transpose_kernel<1><<<dim3(96, 32, 1), blk, 0, stream>>>(Wqkv, 1024, 3072, wqkvT_h, wqkvT_l);
  transpose_kernel<1><<<dim3(32, 32, 1), blk, 0, stream>>>(Wo, 1024, 1024, woT_h, woT_l);
  convw_kernel<<<4096, blk, 0, stream>>>(convw, wcvT_h, wcvT_l);
  transpose_kernel<0><<<dim3(32, 32, 8), blk, 0, stream>>>(expW, 1024, 1024, wexpT, nullptr);
  transpose_kernel<0><<<dim3(128, 32, 1), blk, 0, stream>>>(ffW1, 1024, 4096, wff1T, nullptr);
  transpose_kernel<0><<<dim3(32, 128, 1), blk, 0, stream>>>(ffW2, 4096, 1024, wff2T, nullptr);

  // LN1 -> split planes, COMPACT (only the 4352 rows attention consumes)
  ln_kernel<1, 0, 1><<<4352, blk, 0, stream>>>(x, g1, b1, ln1h, ln1l, nullptr, nullptr, nullptr);
  // QKV on compact rows, split GEMM, fp32 out
  gemm_kernel<3, 0, 0><<<dim3(34, 24), blk, 0, stream>>>(ln1h, ln1l, 1024, wqkvT_h, wqkvT_l, 1024,
      bqkv, nullptr, qkvbuf, nullptr, 3072, 1024, nullptr, nullptr, nullptr);
  // attention (512 threads)
  attn_kernel<<<512, dim3(512), 0, stream>>>(qkvbuf, attnh, attnl);
  // Wo projection + residual -> x1
  gemm_kernel<3, 0, 1><<<dim3(64, 8), blk, 0, stream>>>(attnh, attnl, 1024, woT_h, woT_l, 1024,
      bo, x, x1, nullptr, 1024, 1024, nullptr, nullptr, nullptr);
  // LN2
  ln_kernel<1, 0, 0><<<8192, blk, 0, stream>>>(x1, g2, b2, ln2h, ln2l, nullptr, nullptr, nullptr);
  // conv (3-tap shifted GEMM, exact zero-pad) + residual -> x2
  gemm_kernel<3, 3, 1><<<dim3(64, 8), blk, 0, stream>>>(ln2h, ln2l, 1024, wcvT_h, wcvT_l, 3072,
      convb, x1, x2buf, nullptr, 1024, 3072, nullptr, nullptr, zbuf);
  // LN3 fused with gate logits
  ln_kernel<0, 1, 0><<<8192, blk, 0, stream>>>(x2buf, g3, b3, ln3h, nullptr, gateW, gateb, logits);
  // gate finalize / scan / scatter
  gatefin_kernel<<<32, blk, 0, stream>>>(logits, top2p, top2i, ent, counts);
  scan_kernel<<<1, blk, 0, stream>>>(ent, counts, offs, table, out + 8388608);
  scatter_kernel<<<64, blk, 0, stream>>>(top2i, offs, fill, moe_rows, row2slot);
  // grouped expert GEMM -> eo (f16)
  gemm_kernel<1, 2, 2><<<dim3(136, 8), blk, 0, stream>>>(ln3h, nullptr, 1024, wexpT, nullptr, 1024,
      expb, nullptr, nullptr, eobuf, 1024, 1024, moe_rows, table, nullptr);
  // combine -> x3 (+f16)
  combine_kernel<<<8192, blk, 0, stream>>>(x2buf, eobuf, top2p, row2slot, x3, x3h);
  // FF1 (gelu) -> h
  gemm_kernel<1, 0, 3><<<dim3(64, 32), blk, 0, stream>>>(x3h, nullptr, 1024, wff1T, nullptr, 1024,
      ffb1, nullptr, nullptr, hbuf, 4096, 1024, nullptr, nullptr, nullptr);
  // FF2 + residual -> final output
  gemm_kernel<1, 0, 1><<<dim3(64, 8), blk, 0, stream>>>(hbuf, nullptr, 4096, wff2T, nullptr, 4096,
      ffb2, x3, out, nullptr, 1024, 4096, nullptr, nullptr, nullptr);
}

// Round 12
// 669.441 us; speedup vs baseline: 1.1748x; 1.1112x over previous
//
#include <hip/hip_runtime.h>
#include <cmath>

typedef _Float16 f16;
typedef __attribute__((ext_vector_type(8))) _Float16 f16x8;
typedef __attribute__((ext_vector_type(4))) _Float16 f16x4;
typedef __attribute__((ext_vector_type(4))) float f32x4;

struct TileInfo { int m0, mcnt, e, pad; };

__device__ __forceinline__ void gload16(const void* g, void* l) {
  __builtin_amdgcn_global_load_lds((const __attribute__((address_space(1))) void*)g,
                                   (__attribute__((address_space(3))) void*)l, 16, 0, 0);
}

// fast gelu: 0.5u(1+tanh(c)) = u*e/(e+1), e=exp(2c), c=0.79788456(u+0.044715u^3)
__device__ __forceinline__ float fast_gelu(float u) {
  const float c = u * (0.7978845608028654f + 0.0356774081f * u * u);
  const float t = fminf(2.0f * c, 80.0f);
  const float e = __expf(t);
  return u * (e * __builtin_amdgcn_rcpf(e + 1.0f));
}

// ---------------------------------------------------------------------------
// Unified GEMM (R7-proven; default block mapping — measured traffic-optimal).
//   NPASS==1: BK=64, LDS double-buffer (2x32KB), counted vmcnt(8).
//   NPASS==3: BK=64, single 64KB buffer (Ah/Al/Bh/Bl planes).
// MODE: 0 direct, 1 rowmap, 2 tile-table (MoE), 3 conv (zero-pad via zbuf).
// EPI: 0 f32=acc+bias; 1 f32=res(f32)+acc+bias; 2 f16=acc+bias;
//      3 f16=gelu(acc+bias); 4 f32=res(f16)+acc+bias
// ---------------------------------------------------------------------------
template<int NPASS, int MODE, int EPI>
__global__ __launch_bounds__(256)
void gemm_kernel(const f16* __restrict__ Ah, const f16* __restrict__ Al, int lda,
                 const f16* __restrict__ Bh, const f16* __restrict__ Bl, int ldb,
                 const float* __restrict__ bias, const float* __restrict__ res,
                 float* __restrict__ outf, f16* __restrict__ outh, int ldo, int K,
                 const int* __restrict__ rowmap, const TileInfo* __restrict__ table,
                 const char* __restrict__ zbuf) {
  __shared__ __align__(16) char lds[65536];

  const int tid  = threadIdx.x;
  const int wave = tid >> 6;
  const int lane = tid & 63;

  int m0, mcnt, eidx = 0;
  if (MODE == 2) {
    TileInfo ti = table[blockIdx.x];
    if (ti.mcnt <= 0) return;
    m0 = ti.m0; mcnt = ti.mcnt; eidx = ti.e;
  } else { m0 = blockIdx.x * 128; mcnt = 128; }
  const int n0 = blockIdx.y * 128;

  const f16* Bh_ = Bh;
  const float* bias_ = bias;
  size_t adelta = 0, bdelta = 0;
  if (NPASS == 3) {
    adelta = (size_t)((const char*)Al - (const char*)Ah);
    bdelta = (size_t)((const char*)Bl - (const char*)Bh);
  }
  if (MODE == 2) { Bh_ += ((size_t)eidx << 20); bias_ += eidx * 1024; }

  f32x4 acc[4][4] = {};
  const int wm  = (wave >> 1) * 64;
  const int wn  = (wave & 1) * 64;
  const int fr  = lane & 15;
  const int kgb = (lane >> 4) * 16;
  const int wuni = wave * 1024;

  const int sr    = tid / 8;          // 0..31
  const int cbyte = (tid % 8) * 16;

  if constexpr (NPASS == 1) {
    // ---- BK=64 double-buffered counted-vmcnt (R7, proven) ----
    const char* aSrc[4];
    const char* bSrc[4];
    #pragma unroll
    for (int r = 0; r < 4; ++r) {
      const int mr  = sr + r * 32;
      const int cbs = cbyte ^ ((mr & 7) << 4);
      int gi = m0 + ((mr < mcnt) ? mr : (mcnt - 1));
      if (MODE == 1 || MODE == 2) gi = rowmap[gi];
      aSrc[r] = (const char*)Ah + (size_t)gi * lda * 2 + cbs;
      bSrc[r] = (const char*)Bh_ + (size_t)(n0 + mr) * ldb * 2 + cbs;
    }
    const int NT = K / 64;
    #pragma unroll
    for (int r = 0; r < 4; ++r) {
      gload16(aSrc[r], lds + r * 4096 + wuni);
      gload16(bSrc[r], lds + 16384 + r * 4096 + wuni);
    }
    #pragma unroll
    for (int r = 0; r < 4; ++r) {
      gload16(aSrc[r] + 128, lds + 32768 + r * 4096 + wuni);
      gload16(bSrc[r] + 128, lds + 32768 + 16384 + r * 4096 + wuni);
    }
    asm volatile("s_waitcnt vmcnt(8)" ::: "memory");
    __builtin_amdgcn_s_barrier();

    for (int kt = 0; kt < NT; ++kt) {
      const int c = kt & 1;
      const char* LAp = lds + c * 32768;
      const char* LBp = LAp + 16384;
      f16x8 ah[2][4], bh[2][4];
      #pragma unroll
      for (int kk = 0; kk < 2; ++kk) {
        #pragma unroll
        for (int i = 0; i < 4; ++i) {
          const int ar = wm + i * 16 + fr;
          ah[kk][i] = *(const f16x8*)(LAp + ar * 128 + ((kk * 64 + kgb) ^ ((ar & 7) << 4)));
          const int br = wn + i * 16 + fr;
          bh[kk][i] = *(const f16x8*)(LBp + br * 128 + ((kk * 64 + kgb) ^ ((br & 7) << 4)));
        }
      }
      asm volatile("s_waitcnt lgkmcnt(0)" ::: "memory");
      __builtin_amdgcn_s_barrier();
      if (kt + 2 < NT) {
        const size_t ko = (size_t)(kt + 2) * 128;
        #pragma unroll
        for (int r = 0; r < 4; ++r) {
          gload16(aSrc[r] + ko, lds + c * 32768 + r * 4096 + wuni);
          gload16(bSrc[r] + ko, lds + c * 32768 + 16384 + r * 4096 + wuni);
        }
      }
      #pragma unroll
      for (int kk = 0; kk < 2; ++kk)
        #pragma unroll
        for (int i = 0; i < 4; ++i)
          #pragma unroll
          for (int j = 0; j < 4; ++j)
            acc[i][j] = __builtin_amdgcn_mfma_f32_16x16x32_f16(ah[kk][i], bh[kk][j], acc[i][j], 0, 0, 0);
      if (kt + 2 < NT) asm volatile("s_waitcnt vmcnt(8)" ::: "memory");
      else             asm volatile("s_waitcnt vmcnt(0)" ::: "memory");
      __builtin_amdgcn_s_barrier();
    }
  } else {
    // ---- NPASS==3: single-buffered 3-pass loop (R7, proven) ----
    const char* aSrcB[4]; const char* bSrcB[4];
    int aRowC[4], aCbs[4];
    #pragma unroll
    for (int r = 0; r < 4; ++r) {
      const int mr  = sr + r * 32;
      const int cbs = cbyte ^ ((mr & 7) << 4);
      int gi = m0 + mr;
      if (MODE == 1) gi = rowmap[gi];
      if (MODE == 3) { aRowC[r] = gi; aCbs[r] = cbs; aSrcB[r] = nullptr; }
      else           { aSrcB[r] = (const char*)Ah + (size_t)gi * lda * 2 + cbs; aRowC[r] = 0; aCbs[r] = 0; }
      bSrcB[r] = (const char*)Bh_ + (size_t)(n0 + mr) * ldb * 2 + cbs;
    }
    for (int k0 = 0; k0 < K; k0 += 64) {
      #pragma unroll
      for (int r = 0; r < 4; ++r) {
        const char* as; const char* asl;
        if (MODE == 3) {
          const int tap = k0 >> 10;
          const int kc  = k0 & 1023;
          const int tok = aRowC[r] & 4095;
          const int stk = tok + (tap - 1) * 2;
          if (stk >= 0 && stk < 4096) {
            as  = (const char*)Ah + (size_t)(aRowC[r] + (tap - 1) * 2) * 2048 + kc * 2 + aCbs[r];
            asl = as + adelta;
          } else { as = zbuf; asl = zbuf; }
        } else {
          as  = aSrcB[r] + (size_t)k0 * 2;
          asl = as + adelta;
        }
        gload16(as,  lds + 0     + r * 4096 + wuni);
        gload16(asl, lds + 16384 + r * 4096 + wuni);
        const char* bs = bSrcB[r] + (size_t)k0 * 2;
        gload16(bs,          lds + 32768 + r * 4096 + wuni);
        gload16(bs + bdelta, lds + 49152 + r * 4096 + wuni);
      }
      __syncthreads();
      #pragma unroll
      for (int kk = 0; kk < 2; ++kk) {
        f16x8 ah[4], al[4], bh[4], bl[4];
        #pragma unroll
        for (int i = 0; i < 4; ++i) {
          const int ar = wm + i * 16 + fr;
          const int ao = ar * 128 + ((kk * 64 + kgb) ^ ((ar & 7) << 4));
          ah[i] = *(const f16x8*)(lds + ao);
          al[i] = *(const f16x8*)(lds + 16384 + ao);
          const int br = wn + i * 16 + fr;
          const int bo = br * 128 + ((kk * 64 + kgb) ^ ((br & 7) << 4));
          bh[i] = *(const f16x8*)(lds + 32768 + bo);
          bl[i] = *(const f16x8*)(lds + 49152 + bo);
        }
        #pragma unroll
        for (int i = 0; i < 4; ++i) {
          #pragma unroll
          for (int j = 0; j < 4; ++j) {
            acc[i][j] = __builtin_amdgcn_mfma_f32_16x16x32_f16(ah[i], bh[j], acc[i][j], 0, 0, 0);
            acc[i][j] = __builtin_amdgcn_mfma_f32_16x16x32_f16(ah[i], bl[j], acc[i][j], 0, 0, 0);
            acc[i][j] = __builtin_amdgcn_mfma_f32_16x16x32_f16(al[i], bh[j], acc[i][j], 0, 0, 0);
          }
        }
      }
      __syncthreads();
    }
  }

  #pragma unroll
  for (int i = 0; i < 4; ++i) {
    const int mb = wm + i * 16 + (lane >> 4) * 4;
    #pragma unroll
    for (int j = 0; j < 4; ++j) {
      const int nc = n0 + wn + j * 16 + fr;
      const float bv = bias_[nc];
      #pragma unroll
      for (int q = 0; q < 4; ++q) {
        const int ml = mb + q;
        if (MODE == 2 && ml >= mcnt) continue;
        const size_t orow = (size_t)(m0 + ml);
        float v = acc[i][j][q] + bv;
        if (EPI == 1) v += res[orow * ldo + nc];
        if (EPI == 4) v += (float)((const f16*)res)[orow * ldo + nc];
        if (EPI == 3) v = fast_gelu(v);
        if (EPI <= 1 || EPI == 4) outf[orow * ldo + nc] = v;
        else                      outh[orow * ldo + nc] = (f16)v;
      }
    }
  }
}

// ---------------------------------------------------------------------------
// LayerNorm device body: fp32 in -> f16 hi (+optional lo). WGATE: gate logits.
// ---------------------------------------------------------------------------
template<int WLO, int WGATE>
__device__ __forceinline__ void ln_body(const float* __restrict__ x, int srow, int row,
    const float* __restrict__ g, const float* __restrict__ b,
    f16* __restrict__ oh, f16* __restrict__ ol,
    const float* __restrict__ gW, const float* __restrict__ gb,
    float* __restrict__ logits, char* smraw) {
  float* red  = (float*)smraw;          // 8 floats
  float* gred = (float*)(smraw + 32);   // 32 floats
  const int t = threadIdx.x;
  const float4 v = ((const float4*)(x + (size_t)srow * 1024))[t];
  float s  = v.x + v.y + v.z + v.w;
  float ss = v.x * v.x + v.y * v.y + v.z * v.z + v.w * v.w;
  #pragma unroll
  for (int off = 32; off; off >>= 1) { s += __shfl_down(s, off, 64); ss += __shfl_down(ss, off, 64); }
  if ((t & 63) == 0) { red[t >> 6] = s; red[(t >> 6) + 4] = ss; }
  __syncthreads();
  s  = red[0] + red[1] + red[2] + red[3];
  ss = red[4] + red[5] + red[6] + red[7];
  const float mu  = s * (1.0f / 1024.0f);
  const float var = ss * (1.0f / 1024.0f) - mu * mu;
  const float inv = 1.0f / sqrtf(var + 1e-5f);
  const float4 gv = ((const float4*)g)[t];
  const float4 bv = ((const float4*)b)[t];
  float y[4];
  y[0] = (v.x - mu) * inv * gv.x + bv.x;
  y[1] = (v.y - mu) * inv * gv.y + bv.y;
  y[2] = (v.z - mu) * inv * gv.z + bv.z;
  y[3] = (v.w - mu) * inv * gv.w + bv.w;
  f16x4 hv;
  #pragma unroll
  for (int u = 0; u < 4; ++u) hv[u] = (f16)y[u];
  *(f16x4*)(oh + (size_t)row * 1024 + t * 4) = hv;
  if (WLO) {
    f16x4 lv;
    #pragma unroll
    for (int u = 0; u < 4; ++u) lv[u] = (f16)(y[u] - (float)hv[u]);
    *(f16x4*)(ol + (size_t)row * 1024 + t * 4) = lv;
  }
  if (WGATE) {
    const float* gr = gW + (size_t)(t * 4) * 8;
    float lg[8];
    #pragma unroll
    for (int e = 0; e < 8; ++e)
      lg[e] = y[0] * gr[e] + y[1] * gr[8 + e] + y[2] * gr[16 + e] + y[3] * gr[24 + e];
    #pragma unroll
    for (int m = 1; m < 64; m <<= 1)
      #pragma unroll
      for (int e = 0; e < 8; ++e) lg[e] += __shfl_xor(lg[e], m, 64);
    if ((t & 63) == 0) {
      #pragma unroll
      for (int e = 0; e < 8; ++e) gred[(t >> 6) * 8 + e] = lg[e];
    }
    __syncthreads();
    if (t < 8)
      logits[(size_t)row * 8 + t] = gred[t] + gred[8 + t] + gred[16 + t] + gred[24 + t] + gb[t];
  }
}

template<int WLO, int WGATE>
__global__ __launch_bounds__(256)
void ln_kernel(const float* __restrict__ x, const float* __restrict__ g, const float* __restrict__ b,
               f16* __restrict__ oh, f16* __restrict__ ol,
               const float* __restrict__ gW, const float* __restrict__ gb,
               float* __restrict__ logits) {
  __shared__ __align__(16) char sm[160];
  ln_body<WLO, WGATE>(x, blockIdx.x, blockIdx.x, g, b, oh, ol, gW, gb, logits, sm);
}

// ---------------------------------------------------------------------------
// transpose body: fp32 [R,Cc] -> f16 [Cc,R] hi (+lo)
// ---------------------------------------------------------------------------
template<int SPLIT>
__device__ __forceinline__ void transpose_body(const float* __restrict__ in, int R, int Cc,
    f16* __restrict__ oh, f16* __restrict__ ol, int bx, int by, int z, char* smraw) {
  float (*tile)[33] = (float(*)[33])smraw;
  const size_t mat = (size_t)z * R * Cc;
  in += mat; oh += mat; if (SPLIT) ol += mat;
  const int tx = threadIdx.x & 31, ty = threadIdx.x >> 5;
  const int c = bx * 32 + tx;
  #pragma unroll
  for (int j = 0; j < 32; j += 8) {
    const int r = by * 32 + ty + j;
    tile[ty + j][tx] = in[(size_t)r * Cc + c];
  }
  __syncthreads();
  const int rT = by * 32 + tx;
  #pragma unroll
  for (int j = 0; j < 32; j += 8) {
    const int cT = bx * 32 + ty + j;
    const float v = tile[tx][ty + j];
    const f16 hv = (f16)v;
    oh[(size_t)cT * R + rT] = hv;
    if (SPLIT) ol[(size_t)cT * R + rT] = (f16)(v - (float)hv);
  }
}

// ---------------------------------------------------------------------------
// mega-prep: all weight transposes + convw + LN1(compact) + META zero.
// Branches are block-uniform; one launch replaces 8.
// ---------------------------------------------------------------------------
__global__ __launch_bounds__(256)
void prep_kernel(const float* __restrict__ Wqkv, const float* __restrict__ Wo,
                 const float* __restrict__ convw, const float* __restrict__ expW,
                 const float* __restrict__ ffW1, const float* __restrict__ ffW2,
                 f16* wqkvT_h, f16* wqkvT_l, f16* woT_h, f16* woT_l,
                 f16* wcvT_h, f16* wcvT_l, f16* wexpT, f16* wff1T, f16* wff2T,
                 const float* __restrict__ x, const float* __restrict__ g1,
                 const float* __restrict__ b1, f16* ln1h, f16* ln1l,
                 char* __restrict__ meta) {
  __shared__ __align__(16) char sm[4224];
  int bid = blockIdx.x;
  if (bid < 3072) { transpose_body<1>(Wqkv, 1024, 3072, wqkvT_h, wqkvT_l, bid % 96, bid / 96, 0, sm); return; }
  bid -= 3072;
  if (bid < 1024) { transpose_body<1>(Wo, 1024, 1024, woT_h, woT_l, bid & 31, bid >> 5, 0, sm); return; }
  bid -= 1024;
  if (bid < 4096) {  // convw: [O,I,3] -> BT[o][tap*1024+i] hi/lo
    const int id = bid * 256 + threadIdx.x;
    const int o = id >> 10, i = id & 1023;
    const float* ws = convw + (size_t)o * 3072 + i * 3;
    #pragma unroll
    for (int tap = 0; tap < 3; ++tap) {
      const float v = ws[tap];
      const f16 hv = (f16)v;
      const size_t oi = (size_t)o * 3072 + tap * 1024 + i;
      wcvT_h[oi] = hv;
      wcvT_l[oi] = (f16)(v - (float)hv);
    }
    return;
  }
  bid -= 4096;
  if (bid < 8192) { const int z = bid >> 10, r = bid & 1023; transpose_body<0>(expW, 1024, 1024, wexpT, nullptr, r & 31, r >> 5, z, sm); return; }
  bid -= 8192;
  if (bid < 4096) { transpose_body<0>(ffW1, 1024, 4096, wff1T, nullptr, bid & 127, bid >> 7, 0, sm); return; }
  bid -= 4096;
  if (bid < 4096) { transpose_body<0>(ffW2, 4096, 1024, wff2T, nullptr, bid & 31, bid >> 5, 0, sm); return; }
  bid -= 4096;
  if (bid < 4352) {  // LN1 compact rows
    const int srow = (bid < 2176) ? bid : bid + 1920;
    ln_body<1, 0>(x, srow, bid, g1, b1, ln1h, ln1l, nullptr, nullptr, nullptr, sm);
    return;
  }
  // final block: zero META[0..4096) (counts, fill, table head, zbuf)
  f32x4 z4 = {0.0f, 0.0f, 0.0f, 0.0f};
  ((f32x4*)meta)[threadIdx.x] = z4;
}

// ---------------------------------------------------------------------------
// Windowed attention (512 thr/block): see R6.
// ---------------------------------------------------------------------------
__global__ __launch_bounds__(512, 4)
void attn_kernel(const float* __restrict__ qkv, f16* __restrict__ oh, f16* __restrict__ ol) {
  __shared__ __align__(16) char sm[81920];
  const int bid = blockIdx.x;
  const int b = bid >> 8, h = (bid >> 4) & 15, n = bid & 15;
  const int t = threadIdx.x;
  const size_t rowbase = (size_t)(b * 2176 + n * 128);
  const char* qg = (const char*)(qkv + rowbase * 3072 + h * 64);
  const char* kg = qg + 4096;
  const char* vg = qg + 8192;

  const int srow = t >> 4;
  const int scol = (t & 15) * 16;
  const int wuni = (t >> 6) * 1024;

  const int dt = t >> 4;
  const int et = t & 15;
  float pacc[2][4] = {};

  for (int r = 0; r < 2; ++r) {
    #pragma unroll
    for (int p = 0; p < 4; ++p) {
      const size_t off = (size_t)(r * 128 + p * 32 + srow) * 12288 + scol;
      gload16(qg + off, sm + p * 8192 + wuni);
      gload16(kg + off, sm + 32768 + p * 8192 + wuni);
    }
    __syncthreads();
    #pragma unroll 4
    for (int s = 0; s < 128; ++s) {
      const float2 q2 = *(const float2*)(sm + s * 256 + dt * 8);
      const f32x4 k4 = *(const f32x4*)(sm + 32768 + s * 256 + et * 16);
      #pragma unroll
      for (int z = 0; z < 4; ++z) {
        pacc[0][z] += q2.x * k4[z];
        pacc[1][z] += q2.y * k4[z];
      }
    }
    __syncthreads();
  }

  #pragma unroll
  for (int i = 0; i < 2; ++i) {
    #pragma unroll
    for (int z = 0; z < 4; ++z) pacc[i][z] *= 0.125f;
    float m = fmaxf(fmaxf(pacc[i][0], pacc[i][1]), fmaxf(pacc[i][2], pacc[i][3]));
    m = fmaxf(m, __shfl_xor(m, 1, 16));
    m = fmaxf(m, __shfl_xor(m, 2, 16));
    m = fmaxf(m, __shfl_xor(m, 4, 16));
    m = fmaxf(m, __shfl_xor(m, 8, 16));
    float den = 0.0f;
    #pragma unroll
    for (int z = 0; z < 4; ++z) { pacc[i][z] = __expf(pacc[i][z] - m); den += pacc[i][z]; }
    den += __shfl_xor(den, 1, 16);
    den += __shfl_xor(den, 2, 16);
    den += __shfl_xor(den, 4, 16);
    den += __shfl_xor(den, 8, 16);
    const float dinv = 1.0f / den;
    f32x4 pv;
    #pragma unroll
    for (int z = 0; z < 4; ++z) pv[z] = pacc[i][z] * dinv;
    *(f32x4*)(sm + 65536 + (dt * 2 + i) * 256 + et * 16) = pv;
  }

  const int dt2 = t & 15;
  const int st  = t >> 4;
  const int ch  = h * 64 + (st & 15) * 4;
  const size_t rb2 = (size_t)(b * 4096 + n * 256);

  for (int c = 0; c < 2; ++c) {
    __syncthreads();
    #pragma unroll
    for (int p = 0; p < 4; ++p) {
      const size_t off = (size_t)(c * 128 + p * 32 + srow) * 12288 + scol;
      gload16(vg + off, sm + p * 8192 + wuni);
    }
    __syncthreads();
    float o[16];
    #pragma unroll
    for (int u = 0; u < 16; ++u) o[u] = 0.0f;
    #pragma unroll 2
    for (int e4 = 0; e4 < 16; ++e4) {
      f32x4 p4[4], v4[4];
      #pragma unroll
      for (int i = 0; i < 4; ++i)
        p4[i] = *(const f32x4*)(sm + 65536 + (dt2 * 4 + i) * 256 + e4 * 16);
      #pragma unroll
      for (int j = 0; j < 4; ++j)
        v4[j] = *(const f32x4*)(sm + (st * 4 + j) * 256 + e4 * 16);
      #pragma unroll
      for (int j = 0; j < 4; ++j)
        #pragma unroll
        for (int i = 0; i < 4; ++i) {
          o[j * 4 + i] += v4[j][0] * p4[i][0] + v4[j][1] * p4[i][1]
                        + v4[j][2] * p4[i][2] + v4[j][3] * p4[i][3];
        }
    }
    const int rq = c * 2 + (st >> 4);
    #pragma unroll
    for (int i = 0; i < 4; ++i) {
      const size_t row = rb2 + (size_t)(dt2 * 4 + i) * 4 + rq;
      f16x4 hv, lv;
      #pragma unroll
      for (int j = 0; j < 4; ++j) {
        const float val = o[j * 4 + i];
        hv[j] = (f16)val;
        lv[j] = (f16)(val - (float)hv[j]);
      }
      *(f16x4*)(oh + row * 1024 + ch) = hv;
      *(f16x4*)(ol + row * 1024 + ch) = lv;
    }
  }
}

// ---------------------------------------------------------------------------
// gate finalize
// ---------------------------------------------------------------------------
__global__ __launch_bounds__(256)
void gatefin_kernel(const float* __restrict__ logits, float* __restrict__ top2p,
                    int* __restrict__ top2i, float* __restrict__ ent,
                    int* __restrict__ counts) {
  __shared__ int hist[8];
  const int t = threadIdx.x;
  if (t < 8) hist[t] = 0;
  __syncthreads();
  const int token = blockIdx.x * 256 + t;
  float lg[8];
  const float4 l0 = ((const float4*)(logits + (size_t)token * 8))[0];
  const float4 l1 = ((const float4*)(logits + (size_t)token * 8))[1];
  lg[0] = l0.x; lg[1] = l0.y; lg[2] = l0.z; lg[3] = l0.w;
  lg[4] = l1.x; lg[5] = l1.y; lg[6] = l1.z; lg[7] = l1.w;
  int i0 = 0; float v0 = lg[0];
  #pragma unroll
  for (int e = 1; e < 8; ++e) if (lg[e] > v0) { v0 = lg[e]; i0 = e; }
  int i1 = 0; float v1 = -1e30f;
  #pragma unroll
  for (int e = 0; e < 8; ++e) if (e != i0 && lg[e] > v1) { v1 = lg[e]; i1 = e; }
  float den = 0.0f; float pr[8];
  #pragma unroll
  for (int e = 0; e < 8; ++e) { pr[e] = __expf(lg[e] - v0); den += pr[e]; }
  const float dinv = 1.0f / den;
  float H = 0.0f, p0 = 0.0f, p1 = 0.0f;
  #pragma unroll
  for (int e = 0; e < 8; ++e) {
    const float p = pr[e] * dinv;
    H -= p * __logf(p + 1e-10f);
    if (e == i0) p0 = p;
    if (e == i1) p1 = p;
  }
  ent[token] = H;
  top2p[token * 2] = p0; top2p[token * 2 + 1] = p1;
  top2i[token * 2] = i0; top2i[token * 2 + 1] = i1;
  atomicAdd(&hist[i0], 1);
  atomicAdd(&hist[i1], 1);
  __syncthreads();
  if (t < 8) atomicAdd(&counts[t], hist[t]);
}

// ---------------------------------------------------------------------------
// scatter fused with scan: each block derives offs locally (8 adds); block 0
// additionally computes entropy mean, usage penalty, aux, and the tile table.
// ---------------------------------------------------------------------------
__global__ __launch_bounds__(256)
void scatter_fused(const float* __restrict__ ent, const int* __restrict__ counts,
                   const int* __restrict__ top2i, int* __restrict__ fill,
                   int* __restrict__ moe_rows, int* __restrict__ row2slot,
                   TileInfo* __restrict__ table, float* __restrict__ auxout) {
  __shared__ int loffs[8];
  __shared__ int hist[8];
  __shared__ int base[8];
  __shared__ float red[256];
  const int t = threadIdx.x;
  if (t == 0) { int off = 0; for (int e = 0; e < 8; ++e) { loffs[e] = off; off += counts[e]; } }
  if (t < 8) hist[t] = 0;
  __syncthreads();
  const int id = blockIdx.x * 256 + t;  // 16384
  const int e = top2i[id];
  const int myrank = atomicAdd(&hist[e], 1);
  __syncthreads();
  if (t < 8) base[t] = atomicAdd(&fill[t], hist[t]);
  __syncthreads();
  const int row = loffs[e] + base[e] + myrank;
  moe_rows[row] = id >> 1;
  row2slot[id] = row;
  if (blockIdx.x == 0) {
    float s = 0.0f;
    for (int k = 0; k < 32; ++k) s += ent[t + (k << 8)];
    red[t] = s; __syncthreads();
    for (int hh = 128; hh > 0; hh >>= 1) { if (t < hh) red[t] += red[t + hh]; __syncthreads(); }
    if (t == 0) {
      const float entmean = red[0] * (1.0f / 8192.0f);
      float pen = 0.0f; int nt = 0;
      for (int e2 = 0; e2 < 8; ++e2) {
        const int c = counts[e2];
        for (int m = 0; m < c; m += 128) {
          table[nt].m0 = loffs[e2] + m;
          table[nt].mcnt = (c - m < 128) ? (c - m) : 128;
          table[nt].e = e2; table[nt].pad = 0;
          ++nt;
        }
        const float fr = (float)c * (1.0f / 8192.0f) - 0.3f;
        pen += (fr > 0.0f) ? fr : 0.0f;
      }
      for (; nt < 160; ++nt) { table[nt].m0 = 0; table[nt].mcnt = 0; table[nt].e = 0; table[nt].pad = 0; }
      auxout[0] = 0.1f * entmean + pen;
    }
  }
}

// x3h = (f16)(x2 + p0*eo[r0] + p1*eo[r1])  — f16-only (downstream of gate)
__global__ __launch_bounds__(256)
void combine_kernel(const float* __restrict__ x2, const f16* __restrict__ eo,
                    const float* __restrict__ top2p, const int* __restrict__ row2slot,
                    f16* __restrict__ x3h) {
  const int n = blockIdx.x;
  const int t = threadIdx.x;
  const int r0 = row2slot[n * 2], r1 = row2slot[n * 2 + 1];
  const float p0 = top2p[n * 2], p1 = top2p[n * 2 + 1];
  const float4 xv = ((const float4*)(x2 + (size_t)n * 1024))[t];
  const f16x4 e0 = ((const f16x4*)(eo + (size_t)r0 * 1024))[t];
  const f16x4 e1 = ((const f16x4*)(eo + (size_t)r1 * 1024))[t];
  f16x4 hv;
  hv[0] = (f16)(xv.x + p0 * (float)e0[0] + p1 * (float)e1[0]);
  hv[1] = (f16)(xv.y + p0 * (float)e0[1] + p1 * (float)e1[1]);
  hv[2] = (f16)(xv.z + p0 * (float)e0[2] + p1 * (float)e1[2]);
  hv[3] = (f16)(xv.w + p0 * (float)e0[3] + p1 * (float)e1[3]);
  ((f16x4*)(x3h + (size_t)n * 1024))[t] = hv;
}

// ---------------------------------------------------------------------------
extern "C" void kernel_launch(void* const* d_in, const int* in_sizes, int n_in,
                              void* d_out, int out_size, void* d_ws, size_t ws_size,
                              hipStream_t stream) {
  (void)in_sizes; (void)n_in; (void)out_size; (void)ws_size;
  const float* x     = (const float*)d_in[0];
  const float* g1    = (const float*)d_in[1];
  const float* b1    = (const float*)d_in[2];
  const float* g2    = (const float*)d_in[3];
  const float* b2    = (const float*)d_in[4];
  const float* g3    = (const float*)d_in[5];
  const float* b3    = (const float*)d_in[6];
  const float* Wqkv  = (const float*)d_in[7];
  const float* bqkv  = (const float*)d_in[8];
  const float* Wo    = (const float*)d_in[9];
  const float* bo    = (const float*)d_in[10];
  const float* convw = (const float*)d_in[11];
  const float* convb = (const float*)d_in[12];
  const float* gateW = (const float*)d_in[13];
  const float* gateb = (const float*)d_in[14];
  const float* expW  = (const float*)d_in[15];
  const float* expb  = (const float*)d_in[16];
  const float* ffW1  = (const float*)d_in[17];
  const float* ffb1  = (const float*)d_in[18];
  const float* ffW2  = (const float*)d_in[19];
  const float* ffb2  = (const float*)d_in[20];
  float* out = (float*)d_out;

  char* W = (char*)d_ws;
  f16* wqkvT_h = (f16*)(W + 0);
  f16* wqkvT_l = (f16*)(W + 6291456);
  f16* woT_h   = (f16*)(W + 12582912);
  f16* woT_l   = (f16*)(W + 14680064);
  f16* wcvT_h  = (f16*)(W + 16777216);
  f16* wcvT_l  = (f16*)(W + 23068672);
  f16* wexpT   = (f16*)(W + 29360128);
  f16* wff1T   = (f16*)(W + 46137344);
  f16* wff2T   = (f16*)(W + 54525952);
  char* META   = W + 62914560;
  int* counts    = (int*)(META);
  int* fill      = (int*)(META + 32);
  TileInfo* table = (TileInfo*)(META + 128);
  char* zbuf     = META + 3072;
  float* ent     = (float*)(META + 24576);
  float* top2p   = (float*)(META + 57344);
  int* top2i     = (int*)(META + 122880);
  int* moe_rows  = (int*)(META + 188416);
  int* row2slot  = (int*)(META + 253952);
  float* logits  = (float*)(META + 327680);
  char* SA = W + 63963136;
  char* SB = W + 97517568;
  char* SC = W + 164626432;
  char* SD = W + 198180864;

  f16* ln1h = (f16*)SA;            f16* ln1l = (f16*)(SA + 16777216);
  f16* ln2h = ln1h;                f16* ln2l = ln1l;
  f16* ln3h = ln1h;                f16* x3h  = (f16*)(SA + 16777216);
  float* qkvbuf = (float*)SB;
  float* x2buf  = (float*)SB;
  f16*   hbuf   = (f16*)SB;
  f16* attnh = (f16*)SC;           f16* attnl = (f16*)(SC + 16777216);
  float* x1 = (float*)SD;
  f16* eobuf = (f16*)SD;

  dim3 blk(256);
  // mega-prep: 5 transposes + convw + LN1(compact) + META zero (one launch)
  prep_kernel<<<28929, blk, 0, stream>>>(Wqkv, Wo, convw, expW, ffW1, ffW2,
      wqkvT_h, wqkvT_l, woT_h, woT_l, wcvT_h, wcvT_l, wexpT, wff1T, wff2T,
      x, g1, b1, ln1h, ln1l, META);
  // QKV on compact rows, split GEMM, fp32 out
  gemm_kernel<3, 0, 0><<<dim3(34, 24), blk, 0, stream>>>(ln1h, ln1l, 1024, wqkvT_h, wqkvT_l, 1024,
      bqkv, nullptr, qkvbuf, nullptr, 3072, 1024, nullptr, nullptr, nullptr);
  // attention (512 threads)
  attn_kernel<<<512, dim3(512), 0, stream>>>(qkvbuf, attnh, attnl);
  // Wo projection + residual -> x1
  gemm_kernel<3, 0, 1><<<dim3(64, 8), blk, 0, stream>>>(attnh, attnl, 1024, woT_h, woT_l, 1024,
      bo, x, x1, nullptr, 1024, 1024, nullptr, nullptr, nullptr);
  // LN2
  ln_kernel<1, 0><<<8192, blk, 0, stream>>>(x1, g2, b2, ln2h, ln2l, nullptr, nullptr, nullptr);
  // conv (3-tap shifted GEMM, exact zero-pad) + residual -> x2
  gemm_kernel<3, 3, 1><<<dim3(64, 8), blk, 0, stream>>>(ln2h, ln2l, 1024, wcvT_h, wcvT_l, 3072,
      convb, x1, x2buf, nullptr, 1024, 3072, nullptr, nullptr, zbuf);
  // LN3 fused with gate logits
  ln_kernel<0, 1><<<8192, blk, 0, stream>>>(x2buf, g3, b3, ln3h, nullptr, gateW, gateb, logits);
  // gate finalize / fused scan+scatter
  gatefin_kernel<<<32, blk, 0, stream>>>(logits, top2p, top2i, ent, counts);
  scatter_fused<<<64, blk, 0, stream>>>(ent, counts, top2i, fill, moe_rows, row2slot,
      table, out + 8388608);
  // grouped expert GEMM -> eo (f16)
  gemm_kernel<1, 2, 2><<<dim3(136, 8), blk, 0, stream>>>(ln3h, nullptr, 1024, wexpT, nullptr, 1024,
      expb, nullptr, nullptr, eobuf, 1024, 1024, moe_rows, table, nullptr);
  // combine -> x3h (f16 only; downstream of gate tolerance-safe)
  combine_kernel<<<8192, blk, 0, stream>>>(x2buf, eobuf, top2p, row2slot, x3h);
  // FF1 (gelu) -> h
  gemm_kernel<1, 0, 3><<<dim3(64, 32), blk, 0, stream>>>(x3h, nullptr, 1024, wff1T, nullptr, 1024,
      ffb1, nullptr, nullptr, hbuf, 4096, 1024, nullptr, nullptr, nullptr);
  // FF2 + f16 residual -> final output
  gemm_kernel<1, 0, 4><<<dim3(64, 8), blk, 0, stream>>>(hbuf, nullptr, 4096, wff2T, nullptr, 4096,
      ffb2, (const float*)x3h, out, nullptr, 1024, 4096, nullptr, nullptr, nullptr);
}